// Round 6
// baseline (645.430 us; speedup 1.0000x reference)
//
#include <hip/hip_runtime.h>
#include <math.h>

typedef __attribute__((ext_vector_type(4))) float f32x4;
typedef __attribute__((ext_vector_type(8))) _Float16 f16x8;

__device__ __forceinline__ f32x4 mfma16h(f16x8 a, f16x8 b, f32x4 c){
  return __builtin_amdgcn_mfma_f32_16x16x32_f16(a, b, c, 0, 0, 0);
}
__device__ __forceinline__ void gload_lds16(const void* g, void* l){
  __builtin_amdgcn_global_load_lds((const __attribute__((address_space(1))) void*)g,
                                   (__attribute__((address_space(3))) void*)l, 16, 0, 0);
}

#define EXPC 0.1803368801111204f   // 0.125 * log2(e)

// ---------------- weight stats: alpha=mean(w), beta-sum=sum|w| ----------------
__global__ __launch_bounds__(256) void k_wstats(const float* __restrict__ w1, const float* __restrict__ w2,
                                                double* __restrict__ dsum, double* __restrict__ dabs){
  const int mat = blockIdx.y;
  const float* wp = (mat < 6) ? (w1 + (size_t)mat*1048576) : (w2 + (size_t)(mat-6)*1048576);
  const f32x4* wv = (const f32x4*)wp + (size_t)blockIdx.x*8192;
  double s = 0.0, a = 0.0;
  for (int j = 0; j < 32; j++){
    f32x4 v = wv[j*256 + threadIdx.x];
    s += (double)v.x + (double)v.y + (double)v.z + (double)v.w;
    a += (double)fabsf(v.x) + (double)fabsf(v.y) + (double)fabsf(v.z) + (double)fabsf(v.w);
  }
  for (int d = 1; d < 64; d <<= 1){ s += __shfl_xor(s, d); a += __shfl_xor(a, d); }
  __shared__ double red[8];
  const int w = threadIdx.x >> 6;
  if ((threadIdx.x & 63) == 0){ red[w*2] = s; red[w*2+1] = a; }
  __syncthreads();
  if (threadIdx.x == 0){
    double S = red[0]+red[2]+red[4]+red[6], A = red[1]+red[3]+red[5]+red[7];
    atomicAdd(&dsum[mat], S);
    atomicAdd(&dabs[mat], A);
  }
}

// ---------------- binarize weights to fp16 {-1,0,+1}, swizzled GEMM-B layout ----------------
// layout: wb[mat][n][ (k&~63) + ((k&63) ^ 8*(n&7)) ]
__global__ __launch_bounds__(256) void k_binarize(const float* __restrict__ w1, const float* __restrict__ w2,
                                                  const double* __restrict__ dsum, _Float16* __restrict__ wb){
  const int blk = blockIdx.x;          // 6144 blocks, 512 per matrix
  const int mat = blk >> 9;
  const float alpha = (float)(dsum[mat] * (1.0/1048576.0));
  const float* wp = (mat < 6) ? (w1 + (size_t)mat*1048576) : (w2 + (size_t)(mat-6)*1048576);
  const size_t off = (size_t)(blk & 511)*2048 + (size_t)threadIdx.x*8;
  const int n = (int)(off >> 10), k = (int)(off & 1023);
  f32x4 v0 = *(const f32x4*)(wp + off), v1 = *(const f32x4*)(wp + off + 4);
  float vv[8] = {v0.x,v0.y,v0.z,v0.w,v1.x,v1.y,v1.z,v1.w};
  f16x8 pk;
  #pragma unroll
  for (int e = 0; e < 8; e++){
    float d = vv[e] - alpha;
    pk[e] = d > 0.f ? (_Float16)1.0f : (d < 0.f ? (_Float16)(-1.0f) : (_Float16)0.0f);
  }
  const size_t addr = (size_t)mat*1048576 + (size_t)n*1024 + (size_t)((k & ~63) + ((k & 63) ^ ((n&7)*8)));
  *(f16x8*)&wb[addr] = pk;
}

// ---------------- presplit: x (fp32) -> fp16 hi/lo in K-layout and V^T-layout ----------------
// K:  Kh/Kl[bh][n][ d ^ 8*(n&7) ]           (row n, 64 d)
// VT: Vh/Vl[bh][d][ t*64 + ((n&63) ^ 8*(d&7)) ]
__global__ __launch_bounds__(256) void k_presplit(const float* __restrict__ x,
                                                  _Float16* __restrict__ Kh, _Float16* __restrict__ Kl,
                                                  _Float16* __restrict__ Vh, _Float16* __restrict__ Vl){
  __shared__ _Float16 lh[64*72], ll[64*72];
  const int t = blockIdx.x, bh = blockIdx.y, b = bh>>4, h = bh&15;
  const int n = threadIdx.x>>2, c0 = (threadIdx.x&3)*16;
  const float* src = x + (size_t)b*1048576 + (size_t)(t*64+n)*1024 + h*64 + c0;
  const size_t kbase = ((size_t)bh*1024 + t*64 + n)*64;
  const int sw = (n&7)*8;
  #pragma unroll
  for (int j = 0; j < 2; j++){
    f32x4 v0 = *(const f32x4*)(src + j*8);
    f32x4 v1 = *(const f32x4*)(src + j*8 + 4);
    float vv[8] = {v0.x,v0.y,v0.z,v0.w,v1.x,v1.y,v1.z,v1.w};
    f16x8 Hv, Lv;
    #pragma unroll
    for (int e = 0; e < 8; e++){
      _Float16 hh = (_Float16)vv[e];
      Hv[e] = hh; Lv[e] = (_Float16)(vv[e] - (float)hh);
      const int d = c0 + j*8 + e;
      lh[d*72 + n] = Hv[e]; ll[d*72 + n] = Lv[e];
    }
    const int db = c0 + j*8;
    *(f16x8*)&Kh[kbase + (db ^ sw)] = Hv;
    *(f16x8*)&Kl[kbase + (db ^ sw)] = Lv;
  }
  __syncthreads();
  const int d = threadIdx.x>>2, n0c = (threadIdx.x&3)*16;
  const size_t vbase = ((size_t)bh*64 + d)*1024 + t*64;
  const int sw2 = (d&7)*8;
  #pragma unroll
  for (int j = 0; j < 2; j++){
    f16x8 Hv, Lv;
    #pragma unroll
    for (int e = 0; e < 8; e++){
      Hv[e] = lh[d*72 + n0c + j*8 + e];
      Lv[e] = ll[d*72 + n0c + j*8 + e];
    }
    const int nb = n0c + j*8;
    *(f16x8*)&Vh[vbase + (nb ^ sw2)] = Hv;
    *(f16x8*)&Vl[vbase + (nb ^ sw2)] = Lv;
  }
}

// ---------------- flash attention, split-fp16 MFMA, K-split over 2 halves ----------------
// grid (32 bh, 16 qt, 2 key-halves), 256 thr. Writes UNNORMALIZED partial O (f32)
// and per-row (m*EXPC, l) for the flash combine. No residual here.
__global__ __launch_bounds__(256) void k_attn(const _Float16* __restrict__ Kh, const _Float16* __restrict__ Kl,
                                              const _Float16* __restrict__ Vh, const _Float16* __restrict__ Vl,
                                              float* __restrict__ Op, float* __restrict__ mlb){
  __shared__ _Float16 smb[24576];   // 48 KB
  _Float16* kt_h = smb;
  _Float16* kt_l = smb + 4096;
  _Float16* vt_h = smb + 8192;
  _Float16* vt_l = smb + 12288;
  _Float16* ps_h = smb + 16384;     // aliased: Q staging, then P hi
  _Float16* ps_l = smb + 20480;     // aliased: Q staging, then P lo
  const int tid = threadIdx.x, w = tid>>6, l = tid&63, g = l>>4, r16 = l&15;
  const int bh = blockIdx.x, qt = blockIdx.y, kseg = blockIdx.z;
  const int swr = (r16&7)*8;
  // stage Q (rows qt*64..) into ps region, linear copy (swizzle already in global)
  const _Float16* Qsh = Kh + ((size_t)bh*1024 + qt*64)*64;
  const _Float16* Qsl = Kl + ((size_t)bh*1024 + qt*64)*64;
  #pragma unroll
  for (int j = 0; j < 2; j++){
    const int cb = (j*4 + w)*64;
    gload_lds16(Qsh + (size_t)(cb + l)*8, ps_h + cb*8);
    gload_lds16(Qsl + (size_t)(cb + l)*8, ps_l + cb*8);
  }
  __syncthreads();
  const int qrow = w*16 + r16;
  const f16x8 aqh0 = *(const f16x8*)&ps_h[qrow*64 + ((g*8) ^ swr)];
  const f16x8 aqh1 = *(const f16x8*)&ps_h[qrow*64 + ((32 + g*8) ^ swr)];
  const f16x8 aql0 = *(const f16x8*)&ps_l[qrow*64 + ((g*8) ^ swr)];
  const f16x8 aql1 = *(const f16x8*)&ps_l[qrow*64 + ((32 + g*8) ^ swr)];
  __syncthreads();
  float mI[4], lI[4]; f32x4 acc[4];
  #pragma unroll
  for (int i = 0; i < 4; i++){ mI[i] = -1e30f; lI[i] = 0.f; acc[i] = (f32x4){0.f,0.f,0.f,0.f}; }
  const _Float16* Kbh = Kh + (size_t)bh*65536;
  const _Float16* Kbl = Kl + (size_t)bh*65536;
  for (int tt = 0; tt < 8; tt++){
    const int t = (kseg<<3) + tt;
    __syncthreads();
    #pragma unroll
    for (int j = 0; j < 2; j++){
      const int cb = (j*4 + w)*64;
      const int c  = cb + l;
      gload_lds16(Kbh + (size_t)t*4096 + (size_t)c*8, kt_h + cb*8);
      gload_lds16(Kbl + (size_t)t*4096 + (size_t)c*8, kt_l + cb*8);
      gload_lds16(Vh + ((size_t)bh*64 + (c>>3))*1024 + t*64 + (c&7)*8, vt_h + cb*8);
      gload_lds16(Vl + ((size_t)bh*64 + (c>>3))*1024 + t*64 + (c&7)*8, vt_l + cb*8);
    }
    __syncthreads();
    // QK^T, 3-term split; scores kept RAW (0.125*log2e folded into exp2)
    f32x4 s[4];
    #pragma unroll
    for (int c = 0; c < 4; c++){
      const int rk = c*16 + r16;
      const f16x8 kh0 = *(const f16x8*)&kt_h[rk*64 + ((g*8) ^ swr)];
      const f16x8 kh1 = *(const f16x8*)&kt_h[rk*64 + ((32+g*8) ^ swr)];
      const f16x8 kl0 = *(const f16x8*)&kt_l[rk*64 + ((g*8) ^ swr)];
      const f16x8 kl1 = *(const f16x8*)&kt_l[rk*64 + ((32+g*8) ^ swr)];
      f32x4 z = (f32x4){0.f,0.f,0.f,0.f};
      z = mfma16h(aqh0, kh0, z);
      z = mfma16h(aqh1, kh1, z);
      z = mfma16h(aql0, kh0, z);
      z = mfma16h(aql1, kh1, z);
      z = mfma16h(aqh0, kl0, z);
      z = mfma16h(aqh1, kl1, z);
      s[c] = z;
    }
    // online softmax in exp2 domain (rows = g*4+i per lane-group)
    float rmax[4], rsum[4], fac[4], mnC[4];
    #pragma unroll
    for (int i = 0; i < 4; i++) rmax[i] = fmaxf(fmaxf(s[0][i],s[1][i]), fmaxf(s[2][i],s[3][i]));
    for (int d = 1; d < 16; d <<= 1)
      #pragma unroll
      for (int i = 0; i < 4; i++) rmax[i] = fmaxf(rmax[i], __shfl_xor(rmax[i], d));
    #pragma unroll
    for (int i = 0; i < 4; i++){
      float mn = fmaxf(mI[i], rmax[i]);
      fac[i] = exp2f((mI[i] - mn)*EXPC);
      mI[i] = mn; mnC[i] = mn*EXPC; rsum[i] = 0.f;
    }
    #pragma unroll
    for (int c = 0; c < 4; c++)
      #pragma unroll
      for (int i = 0; i < 4; i++){
        float p = exp2f(fmaf(s[c][i], EXPC, -mnC[i]));
        _Float16 ph = (_Float16)p;
        const int prow = w*16 + g*4 + i;
        const int pcol = (c*16 + r16) ^ ((2*g + (i>>1))*8);   // XOR by 8*((prow>>1)&7)
        ps_h[prow*64 + pcol] = ph;
        ps_l[prow*64 + pcol] = (_Float16)(p - (float)ph);
        rsum[i] += p;
      }
    for (int d = 1; d < 16; d <<= 1)
      #pragma unroll
      for (int i = 0; i < 4; i++) rsum[i] += __shfl_xor(rsum[i], d);
    #pragma unroll
    for (int i = 0; i < 4; i++) lI[i] = lI[i]*fac[i] + rsum[i];
    #pragma unroll
    for (int dc = 0; dc < 4; dc++)
      #pragma unroll
      for (int i = 0; i < 4; i++) acc[dc][i] *= fac[i];
    // PV, 3-term split; ps rows are wave-private (per-wave DS ordering suffices)
    const int psw = (r16>>1)*8;
    #pragma unroll
    for (int ks = 0; ks < 2; ks++){
      const f16x8 aph = *(const f16x8*)&ps_h[(w*16+r16)*64 + ((ks*32 + g*8) ^ psw)];
      const f16x8 apl = *(const f16x8*)&ps_l[(w*16+r16)*64 + ((ks*32 + g*8) ^ psw)];
      #pragma unroll
      for (int dc = 0; dc < 4; dc++){
        const int vr = dc*16 + r16;
        const f16x8 bvh = *(const f16x8*)&vt_h[vr*64 + ((ks*32 + g*8) ^ swr)];
        const f16x8 bvl = *(const f16x8*)&vt_l[vr*64 + ((ks*32 + g*8) ^ swr)];
        acc[dc] = mfma16h(aph, bvh, acc[dc]);
        acc[dc] = mfma16h(apl, bvh, acc[dc]);
        acc[dc] = mfma16h(aph, bvl, acc[dc]);
      }
    }
  }
  // epilogue: unnormalized partial O + (m*EXPC, l)
  float* Ob = Op + ((size_t)(kseg*32 + bh)*1024 + qt*64)*64;
  #pragma unroll
  for (int dc = 0; dc < 4; dc++)
    #pragma unroll
    for (int i = 0; i < 4; i++)
      Ob[(w*16 + g*4 + i)*64 + dc*16 + r16] = acc[dc][i];
  if (r16 == 0){
    #pragma unroll
    for (int i = 0; i < 4; i++){
      const size_t rix = (size_t)(kseg*32 + bh)*1024 + qt*64 + w*16 + g*4 + i;
      mlb[rix*2]   = mI[i]*EXPC;
      mlb[rix*2+1] = lI[i];
    }
  }
}

// ---------------- flash combine: merge 2 key-halves, normalize, add residual ----------------
__global__ __launch_bounds__(256) void k_combine(const float* __restrict__ Op, const float* __restrict__ mlb,
                                                 const float* __restrict__ xin, float* __restrict__ xout){
  const int qt = blockIdx.x, bh = blockIdx.y, b = bh>>4, h = bh&15;
  const int r = threadIdx.x>>2, c0 = (threadIdx.x&3)*16;
  const int row = qt*64 + r;
  const size_t r0 = (size_t)bh*1024 + row;
  const size_t r1 = (size_t)(32+bh)*1024 + row;
  const float m0 = mlb[r0*2], l0 = mlb[r0*2+1];
  const float m1 = mlb[r1*2], l1 = mlb[r1*2+1];
  const float ms = fmaxf(m0, m1);
  const float f0 = exp2f(m0 - ms), f1 = exp2f(m1 - ms);
  const float inv = 1.f/(f0*l0 + f1*l1);
  const size_t p0 = r0*64 + c0, p1 = r1*64 + c0;
  const size_t xbase = (size_t)b*1048576 + (size_t)row*1024 + h*64 + c0;
  #pragma unroll
  for (int j = 0; j < 4; j++){
    f32x4 o0 = *(const f32x4*)&Op[p0 + j*4];
    f32x4 o1 = *(const f32x4*)&Op[p1 + j*4];
    f32x4 xi = *(const f32x4*)&xin[xbase + j*4];
    f32x4 ov;
    #pragma unroll
    for (int e = 0; e < 4; e++) ov[e] = (f0*o0[e] + f1*o1[e])*inv + xi[e];
    *(f32x4*)&xout[xbase + j*4] = ov;
  }
}

// ---------------- layernorm; SPLIT=1 writes fp16 hi/lo in swizzled A-layout ----------------
template<int SPLIT>
__global__ __launch_bounds__(256) void k_ln(const float* __restrict__ x, const float* __restrict__ gg,
                                            const float* __restrict__ bb, float* __restrict__ outf,
                                            _Float16* __restrict__ Oh, _Float16* __restrict__ Ol){
  const int row = blockIdx.x*4 + (threadIdx.x>>6);
  const int lane = threadIdx.x & 63;
  const float* xr = x + (size_t)row*1024;
  f32x4 v[4];
  float s = 0.f, q = 0.f;
  #pragma unroll
  for (int c = 0; c < 2; c++){
    v[c*2]   = *(const f32x4*)(xr + c*512 + lane*8);
    v[c*2+1] = *(const f32x4*)(xr + c*512 + lane*8 + 4);
    #pragma unroll
    for (int e = 0; e < 4; e++){
      s += v[c*2][e] + v[c*2+1][e];
      q += v[c*2][e]*v[c*2][e] + v[c*2+1][e]*v[c*2+1][e];
    }
  }
  for (int d = 1; d < 64; d <<= 1){ s += __shfl_xor(s,d); q += __shfl_xor(q,d); }
  const float mean = s * (1.f/1024.f);
  const float var  = q * (1.f/1024.f) - mean*mean;
  const float rstd = rsqrtf(var + 1e-5f);
  #pragma unroll
  for (int c = 0; c < 2; c++){
    const int col = c*512 + lane*8;
    f32x4 g0 = *(const f32x4*)(gg + col), g1 = *(const f32x4*)(gg + col + 4);
    f32x4 b0 = *(const f32x4*)(bb + col), b1 = *(const f32x4*)(bb + col + 4);
    float h[8];
    #pragma unroll
    for (int e = 0; e < 4; e++){
      h[e]   = (v[c*2][e]  -mean)*rstd*g0[e] + b0[e];
      h[e+4] = (v[c*2+1][e]-mean)*rstd*g1[e] + b1[e];
    }
    if (SPLIT){
      f16x8 Hv, Lv;
      #pragma unroll
      for (int e = 0; e < 8; e++){
        _Float16 hh = (_Float16)h[e];
        Hv[e] = hh; Lv[e] = (_Float16)(h[e] - (float)hh);
      }
      const size_t addr = (size_t)row*1024 + c*512 + (lane>>3)*64 + (((lane&7)*8) ^ ((row&7)*8));
      *(f16x8*)&Oh[addr] = Hv;
      *(f16x8*)&Ol[addr] = Lv;
    } else {
      f32x4 o0, o1;
      #pragma unroll
      for (int e = 0; e < 4; e++){ o0[e] = h[e]; o1[e] = h[e+4]; }
      *(f32x4*)(outf + (size_t)row*1024 + col) = o0;
      *(f32x4*)(outf + (size_t)row*1024 + col + 4) = o1;
    }
  }
}

// ---------------- bitlinear GEMM: C[2048,1024] = (Ah+Al).Wb^T * beta ----------------
// BM=BN=64, BK=64, 4 waves (2Mx2N, wave-tile 32x32), double-buffered gload staging.
// MODE 0: GELU -> split fp16 out (swizzled A-layout). MODE 1: += into fp32 residual.
template<int MODE>
__global__ __launch_bounds__(256) void k_gemm(const _Float16* __restrict__ Ah, const _Float16* __restrict__ Al,
                                              const _Float16* __restrict__ Wg,
                                              float* __restrict__ out32,
                                              _Float16* __restrict__ Oh, _Float16* __restrict__ Ol,
                                              const double* __restrict__ dabs_slot){
  __shared__ _Float16 smb[24576];   // 2 x (A-hi 4096 + A-lo 4096 + B 4096)
  const int tid = threadIdx.x, w = tid>>6, l = tid&63, g = l>>4, r16 = l&15;
  const int wm = w>>1, wn = w&1;
  const int n0 = blockIdx.x*64, m0 = blockIdx.y*64;
  const float scale = (float)(*dabs_slot * (1.0/1048576.0));
  const int swr = (r16&7)*8;
  f32x4 acc[2][2] = {};
  #define STAGE(buf, k0) { _Float16* Bp = smb + (buf)*12288;                              \
    _Pragma("unroll")                                                                     \
    for (int j = 0; j < 2; j++){                                                          \
      const int cb = (j*4 + w)*64; const int c = cb + l;                                  \
      const int r = c>>3; const int cc = (c&7)*8;                                         \
      gload_lds16(Ah + (size_t)(m0 + r)*1024 + (k0) + cc, Bp + cb*8);                     \
      gload_lds16(Al + (size_t)(m0 + r)*1024 + (k0) + cc, Bp + 4096 + cb*8);              \
      gload_lds16(Wg + (size_t)(n0 + r)*1024 + (k0) + cc, Bp + 8192 + cb*8);              \
    } }
  STAGE(0, 0);
  __syncthreads();
  for (int t = 0; t < 16; t++){
    if (t < 15) STAGE((t+1)&1, (t+1)*64);
    const _Float16* Bp = smb + (t&1)*12288;
    #pragma unroll
    for (int kk = 0; kk < 2; kk++){
      f16x8 ah[2], al[2], bf[2];
      const int col = (kk*32 + g*8) ^ swr;
      #pragma unroll
      for (int mi = 0; mi < 2; mi++){
        const int row = wm*32 + mi*16 + r16;
        ah[mi] = *(const f16x8*)&Bp[row*64 + col];
        al[mi] = *(const f16x8*)&Bp[4096 + row*64 + col];
      }
      #pragma unroll
      for (int ni = 0; ni < 2; ni++){
        const int row = wn*32 + ni*16 + r16;
        bf[ni] = *(const f16x8*)&Bp[8192 + row*64 + col];
      }
      #pragma unroll
      for (int mi = 0; mi < 2; mi++)
        #pragma unroll
        for (int ni = 0; ni < 2; ni++){
          acc[mi][ni] = mfma16h(ah[mi], bf[ni], acc[mi][ni]);
          acc[mi][ni] = mfma16h(al[mi], bf[ni], acc[mi][ni]);
        }
    }
    __syncthreads();
  }
  #undef STAGE
  #pragma unroll
  for (int mi = 0; mi < 2; mi++)
    #pragma unroll
    for (int ni = 0; ni < 2; ni++)
      #pragma unroll
      for (int i = 0; i < 4; i++){
        const int rr = m0 + wm*32 + mi*16 + g*4 + i;
        const int cc = n0 + wn*32 + ni*16 + r16;
        float vv = acc[mi][ni][i] * scale;
        if (MODE == 0){
          vv = 0.5f*vv*(1.f + erff(vv*0.70710678118f));
          _Float16 hh = (_Float16)vv;
          const size_t addr = (size_t)rr*1024 + (cc & ~63) + ((cc & 63) ^ ((rr&7)*8));
          Oh[addr] = hh;
          Ol[addr] = (_Float16)(vv - (float)hh);
        } else {
          out32[(size_t)rr*1024 + cc] += vv;
        }
      }
}

extern "C" void kernel_launch(void* const* d_in, const int* in_sizes, int n_in,
                              void* d_out, int out_size, void* d_ws, size_t ws_size,
                              hipStream_t stream){
  const float* x_in = (const float*)d_in[0];
  const float* ln_g = (const float*)d_in[1];
  const float* ln_b = (const float*)d_in[2];
  const float* w1   = (const float*)d_in[3];
  const float* w2   = (const float*)d_in[4];
  const float* fg   = (const float*)d_in[5];
  const float* fb   = (const float*)d_in[6];

  char* ws = (char*)d_ws;
  double*   dsum  = (double*)ws;            // 12
  double*   dabs  = (double*)(ws + 96);     // 12
  _Float16* wb = (_Float16*)(ws + 256);     // 12 * 1M fp16 = 24 MB
  size_t o = 256 + 12ull*1048576ull*2ull;
  float* xA = (float*)(ws + o); o += 2048ull*1024*4;
  float* xB = (float*)(ws + o); o += 2048ull*1024*4;
  _Float16* Kh = (_Float16*)(ws + o); o += 2048ull*1024*2;
  _Float16* Kl = (_Float16*)(ws + o); o += 2048ull*1024*2;
  _Float16* Vh = (_Float16*)(ws + o); o += 2048ull*1024*2;
  _Float16* Vl = (_Float16*)(ws + o); o += 2048ull*1024*2;
  _Float16* Ahb = (_Float16*)(ws + o); o += 2048ull*1024*2;
  _Float16* Alb = (_Float16*)(ws + o); o += 2048ull*1024*2;
  _Float16* Ghb = (_Float16*)(ws + o); o += 2048ull*1024*2;
  _Float16* Glb = (_Float16*)(ws + o); o += 2048ull*1024*2;
  float* Op  = (float*)(ws + o); o += 2ull*32*1024*64*4;   // 16.8 MB partial O
  float* mlb = (float*)(ws + o); o += 2ull*32*1024*2*4;    // (m*C, l)

  hipMemsetAsync(ws, 0, 256, stream);
  k_wstats  <<<dim3(32,12), 256, 0, stream>>>(w1, w2, dsum, dabs);
  k_binarize<<<6144,        256, 0, stream>>>(w1, w2, dsum, wb);

  const float* xc = x_in;
  for (int i = 0; i < 6; i++){
    float* xn = (i & 1) ? xB : xA;
    k_presplit<<<dim3(16,32), 256, 0, stream>>>(xc, Kh, Kl, Vh, Vl);
    k_attn    <<<dim3(32,16,2), 256, 0, stream>>>(Kh, Kl, Vh, Vl, Op, mlb);
    k_combine <<<dim3(16,32), 256, 0, stream>>>(Op, mlb, xc, xn);
    k_ln<1>   <<<512, 256, 0, stream>>>(xn, ln_g + (size_t)i*1024, ln_b + (size_t)i*1024,
                                        nullptr, Ahb, Alb);
    k_gemm<0> <<<dim3(16,32), 256, 0, stream>>>(Ahb, Alb, wb + (size_t)i*1048576,
                                                nullptr, Ghb, Glb, &dabs[i]);
    k_gemm<1> <<<dim3(16,32), 256, 0, stream>>>(Ghb, Glb, wb + (size_t)(6+i)*1048576,
                                                xn, nullptr, nullptr, &dabs[6+i]);
    xc = xn;
  }
  k_ln<0><<<512, 256, 0, stream>>>(xc, fg, fb, (float*)d_out, nullptr, nullptr);
}

// Round 7
// 596.257 us; speedup vs baseline: 1.0825x; 1.0825x over previous
//
#include <hip/hip_runtime.h>
#include <math.h>

typedef __attribute__((ext_vector_type(4))) float f32x4;
typedef __attribute__((ext_vector_type(8))) _Float16 f16x8;

__device__ __forceinline__ f32x4 mfma16h(f16x8 a, f16x8 b, f32x4 c){
  return __builtin_amdgcn_mfma_f32_16x16x32_f16(a, b, c, 0, 0, 0);
}
__device__ __forceinline__ void gload_lds16(const void* g, void* l){
  __builtin_amdgcn_global_load_lds((const __attribute__((address_space(1))) void*)g,
                                   (__attribute__((address_space(3))) void*)l, 16, 0, 0);
}

#define EXPC 0.1803368801111204f   // 0.125 * log2(e)

// ---------------- weight stats: alpha=mean(w), beta-sum=sum|w| ----------------
__global__ __launch_bounds__(256) void k_wstats(const float* __restrict__ w1, const float* __restrict__ w2,
                                                double* __restrict__ dsum, double* __restrict__ dabs){
  const int mat = blockIdx.y;
  const float* wp = (mat < 6) ? (w1 + (size_t)mat*1048576) : (w2 + (size_t)(mat-6)*1048576);
  const f32x4* wv = (const f32x4*)wp + (size_t)blockIdx.x*8192;
  double s = 0.0, a = 0.0;
  for (int j = 0; j < 32; j++){
    f32x4 v = wv[j*256 + threadIdx.x];
    s += (double)v.x + (double)v.y + (double)v.z + (double)v.w;
    a += (double)fabsf(v.x) + (double)fabsf(v.y) + (double)fabsf(v.z) + (double)fabsf(v.w);
  }
  for (int d = 1; d < 64; d <<= 1){ s += __shfl_xor(s, d); a += __shfl_xor(a, d); }
  __shared__ double red[8];
  const int w = threadIdx.x >> 6;
  if ((threadIdx.x & 63) == 0){ red[w*2] = s; red[w*2+1] = a; }
  __syncthreads();
  if (threadIdx.x == 0){
    double S = red[0]+red[2]+red[4]+red[6], A = red[1]+red[3]+red[5]+red[7];
    atomicAdd(&dsum[mat], S);
    atomicAdd(&dabs[mat], A);
  }
}

// ---------------- binarize weights to fp16 {-1,0,+1}, swizzled GEMM-B layout ----------------
// layout: wb[mat][n][ (k&~63) + ((k&63) ^ 8*(n&7)) ]
__global__ __launch_bounds__(256) void k_binarize(const float* __restrict__ w1, const float* __restrict__ w2,
                                                  const double* __restrict__ dsum, _Float16* __restrict__ wb){
  const int blk = blockIdx.x;          // 6144 blocks, 512 per matrix
  const int mat = blk >> 9;
  const float alpha = (float)(dsum[mat] * (1.0/1048576.0));
  const float* wp = (mat < 6) ? (w1 + (size_t)mat*1048576) : (w2 + (size_t)(mat-6)*1048576);
  const size_t off = (size_t)(blk & 511)*2048 + (size_t)threadIdx.x*8;
  const int n = (int)(off >> 10), k = (int)(off & 1023);
  f32x4 v0 = *(const f32x4*)(wp + off), v1 = *(const f32x4*)(wp + off + 4);
  float vv[8] = {v0.x,v0.y,v0.z,v0.w,v1.x,v1.y,v1.z,v1.w};
  f16x8 pk;
  #pragma unroll
  for (int e = 0; e < 8; e++){
    float d = vv[e] - alpha;
    pk[e] = d > 0.f ? (_Float16)1.0f : (d < 0.f ? (_Float16)(-1.0f) : (_Float16)0.0f);
  }
  const size_t addr = (size_t)mat*1048576 + (size_t)n*1024 + (size_t)((k & ~63) + ((k & 63) ^ ((n&7)*8)));
  *(f16x8*)&wb[addr] = pk;
}

// ---------------- presplit: x (fp32) -> fp16 hi/lo in K-layout and V^T-layout ----------------
// K:  Kh/Kl[bh][n][ d ^ 8*(n&7) ]           (row n, 64 d)
// VT: Vh/Vl[bh][d][ t*64 + ((n&63) ^ 8*(d&7)) ]
__global__ __launch_bounds__(256) void k_presplit(const float* __restrict__ x,
                                                  _Float16* __restrict__ Kh, _Float16* __restrict__ Kl,
                                                  _Float16* __restrict__ Vh, _Float16* __restrict__ Vl){
  __shared__ _Float16 lh[64*72], ll[64*72];
  const int t = blockIdx.x, bh = blockIdx.y, b = bh>>4, h = bh&15;
  const int n = threadIdx.x>>2, c0 = (threadIdx.x&3)*16;
  const float* src = x + (size_t)b*1048576 + (size_t)(t*64+n)*1024 + h*64 + c0;
  const size_t kbase = ((size_t)bh*1024 + t*64 + n)*64;
  const int sw = (n&7)*8;
  #pragma unroll
  for (int j = 0; j < 2; j++){
    f32x4 v0 = *(const f32x4*)(src + j*8);
    f32x4 v1 = *(const f32x4*)(src + j*8 + 4);
    float vv[8] = {v0.x,v0.y,v0.z,v0.w,v1.x,v1.y,v1.z,v1.w};
    f16x8 Hv, Lv;
    #pragma unroll
    for (int e = 0; e < 8; e++){
      _Float16 hh = (_Float16)vv[e];
      Hv[e] = hh; Lv[e] = (_Float16)(vv[e] - (float)hh);
      const int d = c0 + j*8 + e;
      lh[d*72 + n] = Hv[e]; ll[d*72 + n] = Lv[e];
    }
    const int db = c0 + j*8;
    *(f16x8*)&Kh[kbase + (db ^ sw)] = Hv;
    *(f16x8*)&Kl[kbase + (db ^ sw)] = Lv;
  }
  __syncthreads();
  const int d = threadIdx.x>>2, n0c = (threadIdx.x&3)*16;
  const size_t vbase = ((size_t)bh*64 + d)*1024 + t*64;
  const int sw2 = (d&7)*8;
  #pragma unroll
  for (int j = 0; j < 2; j++){
    f16x8 Hv, Lv;
    #pragma unroll
    for (int e = 0; e < 8; e++){
      Hv[e] = lh[d*72 + n0c + j*8 + e];
      Lv[e] = ll[d*72 + n0c + j*8 + e];
    }
    const int nb = n0c + j*8;
    *(f16x8*)&Vh[vbase + (nb ^ sw2)] = Hv;
    *(f16x8*)&Vl[vbase + (nb ^ sw2)] = Lv;
  }
}

// ---------------- flash attention + residual, split-fp16 MFMA, 2-phase dbuf staging ----------------
// grid (32 bh, 16 qt), 256 thr. K/V double-buffered: STAGE(t+1) issued before compute(t),
// one barrier per tile (drains vmcnt). Defer-rescale (T13) in exp2 domain.
__global__ __launch_bounds__(256) void k_attn(const _Float16* __restrict__ Kh, const _Float16* __restrict__ Kl,
                                              const _Float16* __restrict__ Vh, const _Float16* __restrict__ Vl,
                                              const float* __restrict__ xin, float* __restrict__ xout){
  __shared__ _Float16 smb[40960];   // 80 KB: 2 x 32KB {Kh,Kl,Vh,Vl} dbuf + 16KB Q/P
  _Float16* ps_h = smb + 32768;     // aliased: Q staging, then P hi
  _Float16* ps_l = smb + 36864;     // aliased: Q staging, then P lo
  const int tid = threadIdx.x, w = tid>>6, l = tid&63, g = l>>4, r16 = l&15;
  const int bh = blockIdx.x, qt = blockIdx.y, b = bh>>4, h = bh&15;
  const int swr = (r16&7)*8;
  const _Float16* Kbh = Kh + (size_t)bh*65536;
  const _Float16* Kbl = Kl + (size_t)bh*65536;

  #define ASTAGE(buf, t) { _Float16* Bp = smb + (buf)*16384;                                    \
    _Pragma("unroll")                                                                            \
    for (int j = 0; j < 2; j++){                                                                 \
      const int cb = (j*4 + w)*64; const int c = cb + l;                                         \
      gload_lds16(Kbh + (size_t)(t)*4096 + (size_t)c*8, Bp + cb*8);                              \
      gload_lds16(Kbl + (size_t)(t)*4096 + (size_t)c*8, Bp + 4096 + cb*8);                       \
      gload_lds16(Vh + ((size_t)bh*64 + (c>>3))*1024 + (t)*64 + (c&7)*8, Bp + 8192 + cb*8);      \
      gload_lds16(Vl + ((size_t)bh*64 + (c>>3))*1024 + (t)*64 + (c&7)*8, Bp + 12288 + cb*8);     \
    } }

  // prologue: stage Q into ps region + tile 0 into buf0, one drain
  const _Float16* Qsh = Kbh + (size_t)qt*4096;
  const _Float16* Qsl = Kbl + (size_t)qt*4096;
  #pragma unroll
  for (int j = 0; j < 2; j++){
    const int cb = (j*4 + w)*64;
    gload_lds16(Qsh + (size_t)(cb + l)*8, ps_h + cb*8);
    gload_lds16(Qsl + (size_t)(cb + l)*8, ps_l + cb*8);
  }
  ASTAGE(0, 0);
  __syncthreads();
  const int qrow = w*16 + r16;
  const f16x8 aqh0 = *(const f16x8*)&ps_h[qrow*64 + ((g*8) ^ swr)];
  const f16x8 aqh1 = *(const f16x8*)&ps_h[qrow*64 + ((32 + g*8) ^ swr)];
  const f16x8 aql0 = *(const f16x8*)&ps_l[qrow*64 + ((g*8) ^ swr)];
  const f16x8 aql1 = *(const f16x8*)&ps_l[qrow*64 + ((32 + g*8) ^ swr)];
  __syncthreads();   // Q frags in regs before P writes may touch ps
  float mI[4], lI[4]; f32x4 acc[4];
  #pragma unroll
  for (int i = 0; i < 4; i++){ mI[i] = -1e30f; lI[i] = 0.f; acc[i] = (f32x4){0.f,0.f,0.f,0.f}; }

  for (int t = 0; t < 16; t++){
    if (t < 15) ASTAGE((t+1)&1, t+1);          // prefetch next tile into other buffer
    const _Float16* kt_h = smb + (t&1)*16384;
    const _Float16* kt_l = kt_h + 4096;
    const _Float16* vt_h = kt_h + 8192;
    const _Float16* vt_l = kt_h + 12288;
    // QK^T, 3-term split; scores kept RAW (0.125*log2e folded into exp2)
    f32x4 s[4];
    #pragma unroll
    for (int c = 0; c < 4; c++){
      const int rk = c*16 + r16;
      const f16x8 kh0 = *(const f16x8*)&kt_h[rk*64 + ((g*8) ^ swr)];
      const f16x8 kh1 = *(const f16x8*)&kt_h[rk*64 + ((32+g*8) ^ swr)];
      const f16x8 kl0 = *(const f16x8*)&kt_l[rk*64 + ((g*8) ^ swr)];
      const f16x8 kl1 = *(const f16x8*)&kt_l[rk*64 + ((32+g*8) ^ swr)];
      f32x4 z = (f32x4){0.f,0.f,0.f,0.f};
      z = mfma16h(aqh0, kh0, z);
      z = mfma16h(aqh1, kh1, z);
      z = mfma16h(aql0, kh0, z);
      z = mfma16h(aql1, kh1, z);
      z = mfma16h(aqh0, kl0, z);
      z = mfma16h(aqh1, kl1, z);
      s[c] = z;
    }
    // online softmax in exp2 domain; defer-rescale if max growth <= 44.4 raw (P <= e^8)
    float rmax[4], rsum[4], mnC[4];
    #pragma unroll
    for (int i = 0; i < 4; i++) rmax[i] = fmaxf(fmaxf(s[0][i],s[1][i]), fmaxf(s[2][i],s[3][i]));
    for (int d = 1; d < 16; d <<= 1)
      #pragma unroll
      for (int i = 0; i < 4; i++) rmax[i] = fmaxf(rmax[i], __shfl_xor(rmax[i], d));
    const float dmax = fmaxf(fmaxf(rmax[0]-mI[0], rmax[1]-mI[1]), fmaxf(rmax[2]-mI[2], rmax[3]-mI[3]));
    if (dmax > 44.36f){
      #pragma unroll
      for (int i = 0; i < 4; i++){
        const float mn = fmaxf(mI[i], rmax[i]);
        const float fac = exp2f((mI[i] - mn)*EXPC);
        lI[i] *= fac;
        mI[i] = mn;
        #pragma unroll
        for (int dc = 0; dc < 4; dc++) acc[dc][i] *= fac;
      }
    }
    #pragma unroll
    for (int i = 0; i < 4; i++){ mnC[i] = mI[i]*EXPC; rsum[i] = 0.f; }
    #pragma unroll
    for (int c = 0; c < 4; c++)
      #pragma unroll
      for (int i = 0; i < 4; i++){
        float p = exp2f(fmaf(s[c][i], EXPC, -mnC[i]));
        _Float16 ph = (_Float16)p;
        const int prow = w*16 + g*4 + i;
        const int pcol = (c*16 + r16) ^ ((2*g + (i>>1))*8);   // XOR by 8*((prow>>1)&7)
        ps_h[prow*64 + pcol] = ph;
        ps_l[prow*64 + pcol] = (_Float16)(p - (float)ph);
        rsum[i] += p;
      }
    for (int d = 1; d < 16; d <<= 1)
      #pragma unroll
      for (int i = 0; i < 4; i++) rsum[i] += __shfl_xor(rsum[i], d);
    #pragma unroll
    for (int i = 0; i < 4; i++) lI[i] += rsum[i];
    // PV, 3-term split; ps rows are wave-private (per-wave DS ordering suffices)
    const int psw = (r16>>1)*8;
    #pragma unroll
    for (int ks = 0; ks < 2; ks++){
      const f16x8 aph = *(const f16x8*)&ps_h[(w*16+r16)*64 + ((ks*32 + g*8) ^ psw)];
      const f16x8 apl = *(const f16x8*)&ps_l[(w*16+r16)*64 + ((ks*32 + g*8) ^ psw)];
      #pragma unroll
      for (int dc = 0; dc < 4; dc++){
        const int vr = dc*16 + r16;
        const f16x8 bvh = *(const f16x8*)&vt_h[vr*64 + ((ks*32 + g*8) ^ swr)];
        const f16x8 bvl = *(const f16x8*)&vt_l[vr*64 + ((ks*32 + g*8) ^ swr)];
        acc[dc] = mfma16h(aph, bvh, acc[dc]);
        acc[dc] = mfma16h(apl, bvh, acc[dc]);
        acc[dc] = mfma16h(aph, bvl, acc[dc]);
      }
    }
    __syncthreads();   // drains vmcnt: next buffer staged; all waves done with buf t&1
  }
  #undef ASTAGE
  #pragma unroll
  for (int dc = 0; dc < 4; dc++)
    #pragma unroll
    for (int i = 0; i < 4; i++){
      const int row = qt*64 + w*16 + g*4 + i;
      const size_t idx = (size_t)b*1048576 + (size_t)row*1024 + h*64 + dc*16 + r16;
      xout[idx] = acc[dc][i]/lI[i] + xin[idx];
    }
}

// ---------------- layernorm; SPLIT=1 writes fp16 hi/lo in swizzled A-layout ----------------
template<int SPLIT>
__global__ __launch_bounds__(256) void k_ln(const float* __restrict__ x, const float* __restrict__ gg,
                                            const float* __restrict__ bb, float* __restrict__ outf,
                                            _Float16* __restrict__ Oh, _Float16* __restrict__ Ol){
  const int row = blockIdx.x*4 + (threadIdx.x>>6);
  const int lane = threadIdx.x & 63;
  const float* xr = x + (size_t)row*1024;
  f32x4 v[4];
  float s = 0.f, q = 0.f;
  #pragma unroll
  for (int c = 0; c < 2; c++){
    v[c*2]   = *(const f32x4*)(xr + c*512 + lane*8);
    v[c*2+1] = *(const f32x4*)(xr + c*512 + lane*8 + 4);
    #pragma unroll
    for (int e = 0; e < 4; e++){
      s += v[c*2][e] + v[c*2+1][e];
      q += v[c*2][e]*v[c*2][e] + v[c*2+1][e]*v[c*2+1][e];
    }
  }
  for (int d = 1; d < 64; d <<= 1){ s += __shfl_xor(s,d); q += __shfl_xor(q,d); }
  const float mean = s * (1.f/1024.f);
  const float var  = q * (1.f/1024.f) - mean*mean;
  const float rstd = rsqrtf(var + 1e-5f);
  #pragma unroll
  for (int c = 0; c < 2; c++){
    const int col = c*512 + lane*8;
    f32x4 g0 = *(const f32x4*)(gg + col), g1 = *(const f32x4*)(gg + col + 4);
    f32x4 b0 = *(const f32x4*)(bb + col), b1 = *(const f32x4*)(bb + col + 4);
    float h[8];
    #pragma unroll
    for (int e = 0; e < 4; e++){
      h[e]   = (v[c*2][e]  -mean)*rstd*g0[e] + b0[e];
      h[e+4] = (v[c*2+1][e]-mean)*rstd*g1[e] + b1[e];
    }
    if (SPLIT){
      f16x8 Hv, Lv;
      #pragma unroll
      for (int e = 0; e < 8; e++){
        _Float16 hh = (_Float16)h[e];
        Hv[e] = hh; Lv[e] = (_Float16)(h[e] - (float)hh);
      }
      const size_t addr = (size_t)row*1024 + c*512 + (lane>>3)*64 + (((lane&7)*8) ^ ((row&7)*8));
      *(f16x8*)&Oh[addr] = Hv;
      *(f16x8*)&Ol[addr] = Lv;
    } else {
      f32x4 o0, o1;
      #pragma unroll
      for (int e = 0; e < 4; e++){ o0[e] = h[e]; o1[e] = h[e+4]; }
      *(f32x4*)(outf + (size_t)row*1024 + col) = o0;
      *(f32x4*)(outf + (size_t)row*1024 + col + 4) = o1;
    }
  }
}

// ---------------- bitlinear GEMM: C[2048,1024] = (Ah+Al).Wb^T * beta ----------------
// BM=BN=64, BK=64, 4 waves (2Mx2N, wave-tile 32x32), double-buffered gload staging.
// MODE 0: GELU -> split fp16 out (swizzled A-layout). MODE 1: += into fp32 residual.
template<int MODE>
__global__ __launch_bounds__(256) void k_gemm(const _Float16* __restrict__ Ah, const _Float16* __restrict__ Al,
                                              const _Float16* __restrict__ Wg,
                                              float* __restrict__ out32,
                                              _Float16* __restrict__ Oh, _Float16* __restrict__ Ol,
                                              const double* __restrict__ dabs_slot){
  __shared__ _Float16 smb[24576];   // 2 x (A-hi 4096 + A-lo 4096 + B 4096)
  const int tid = threadIdx.x, w = tid>>6, l = tid&63, g = l>>4, r16 = l&15;
  const int wm = w>>1, wn = w&1;
  const int n0 = blockIdx.x*64, m0 = blockIdx.y*64;
  const float scale = (float)(*dabs_slot * (1.0/1048576.0));
  const int swr = (r16&7)*8;
  f32x4 acc[2][2] = {};
  #define STAGE(buf, k0) { _Float16* Bp = smb + (buf)*12288;                              \
    _Pragma("unroll")                                                                     \
    for (int j = 0; j < 2; j++){                                                          \
      const int cb = (j*4 + w)*64; const int c = cb + l;                                  \
      const int r = c>>3; const int cc = (c&7)*8;                                         \
      gload_lds16(Ah + (size_t)(m0 + r)*1024 + (k0) + cc, Bp + cb*8);                     \
      gload_lds16(Al + (size_t)(m0 + r)*1024 + (k0) + cc, Bp + 4096 + cb*8);              \
      gload_lds16(Wg + (size_t)(n0 + r)*1024 + (k0) + cc, Bp + 8192 + cb*8);              \
    } }
  STAGE(0, 0);
  __syncthreads();
  for (int t = 0; t < 16; t++){
    if (t < 15) STAGE((t+1)&1, (t+1)*64);
    const _Float16* Bp = smb + (t&1)*12288;
    #pragma unroll
    for (int kk = 0; kk < 2; kk++){
      f16x8 ah[2], al[2], bf[2];
      const int col = (kk*32 + g*8) ^ swr;
      #pragma unroll
      for (int mi = 0; mi < 2; mi++){
        const int row = wm*32 + mi*16 + r16;
        ah[mi] = *(const f16x8*)&Bp[row*64 + col];
        al[mi] = *(const f16x8*)&Bp[4096 + row*64 + col];
      }
      #pragma unroll
      for (int ni = 0; ni < 2; ni++){
        const int row = wn*32 + ni*16 + r16;
        bf[ni] = *(const f16x8*)&Bp[8192 + row*64 + col];
      }
      #pragma unroll
      for (int mi = 0; mi < 2; mi++)
        #pragma unroll
        for (int ni = 0; ni < 2; ni++){
          acc[mi][ni] = mfma16h(ah[mi], bf[ni], acc[mi][ni]);
          acc[mi][ni] = mfma16h(al[mi], bf[ni], acc[mi][ni]);
        }
    }
    __syncthreads();
  }
  #undef STAGE
  #pragma unroll
  for (int mi = 0; mi < 2; mi++)
    #pragma unroll
    for (int ni = 0; ni < 2; ni++)
      #pragma unroll
      for (int i = 0; i < 4; i++){
        const int rr = m0 + wm*32 + mi*16 + g*4 + i;
        const int cc = n0 + wn*32 + ni*16 + r16;
        float vv = acc[mi][ni][i] * scale;
        if (MODE == 0){
          vv = 0.5f*vv*(1.f + erff(vv*0.70710678118f));
          _Float16 hh = (_Float16)vv;
          const size_t addr = (size_t)rr*1024 + (cc & ~63) + ((cc & 63) ^ ((rr&7)*8));
          Oh[addr] = hh;
          Ol[addr] = (_Float16)(vv - (float)hh);
        } else {
          out32[(size_t)rr*1024 + cc] += vv;
        }
      }
}

extern "C" void kernel_launch(void* const* d_in, const int* in_sizes, int n_in,
                              void* d_out, int out_size, void* d_ws, size_t ws_size,
                              hipStream_t stream){
  const float* x_in = (const float*)d_in[0];
  const float* ln_g = (const float*)d_in[1];
  const float* ln_b = (const float*)d_in[2];
  const float* w1   = (const float*)d_in[3];
  const float* w2   = (const float*)d_in[4];
  const float* fg   = (const float*)d_in[5];
  const float* fb   = (const float*)d_in[6];

  char* ws = (char*)d_ws;
  double*   dsum  = (double*)ws;            // 12
  double*   dabs  = (double*)(ws + 96);     // 12
  _Float16* wb = (_Float16*)(ws + 256);     // 12 * 1M fp16 = 24 MB
  size_t o = 256 + 12ull*1048576ull*2ull;
  float* xA = (float*)(ws + o); o += 2048ull*1024*4;
  float* xB = (float*)(ws + o); o += 2048ull*1024*4;
  _Float16* Kh = (_Float16*)(ws + o); o += 2048ull*1024*2;
  _Float16* Kl = (_Float16*)(ws + o); o += 2048ull*1024*2;
  _Float16* Vh = (_Float16*)(ws + o); o += 2048ull*1024*2;
  _Float16* Vl = (_Float16*)(ws + o); o += 2048ull*1024*2;
  _Float16* Ahb = (_Float16*)(ws + o); o += 2048ull*1024*2;
  _Float16* Alb = (_Float16*)(ws + o); o += 2048ull*1024*2;
  _Float16* Ghb = (_Float16*)(ws + o); o += 2048ull*1024*2;
  _Float16* Glb = (_Float16*)(ws + o); o += 2048ull*1024*2;

  hipMemsetAsync(ws, 0, 256, stream);
  k_wstats  <<<dim3(32,12), 256, 0, stream>>>(w1, w2, dsum, dabs);
  k_binarize<<<6144,        256, 0, stream>>>(w1, w2, dsum, wb);

  const float* xc = x_in;
  for (int i = 0; i < 6; i++){
    float* xn = (i & 1) ? xB : xA;
    k_presplit<<<dim3(16,32), 256, 0, stream>>>(xc, Kh, Kl, Vh, Vl);
    k_attn    <<<dim3(32,16), 256, 0, stream>>>(Kh, Kl, Vh, Vl, xc, xn);
    k_ln<1>   <<<512, 256, 0, stream>>>(xn, ln_g + (size_t)i*1024, ln_b + (size_t)i*1024,
                                        nullptr, Ahb, Alb);
    k_gemm<0> <<<dim3(16,32), 256, 0, stream>>>(Ahb, Alb, wb + (size_t)i*1048576,
                                                nullptr, Ghb, Glb, &dabs[i]);
    k_gemm<1> <<<dim3(16,32), 256, 0, stream>>>(Ghb, Glb, wb + (size_t)(6+i)*1048576,
                                                xn, nullptr, nullptr, &dabs[6+i]);
    xc = xn;
  }
  k_ln<0><<<512, 256, 0, stream>>>(xc, fg, fb, (float*)d_out, nullptr, nullptr);
}

// Round 9
// 520.448 us; speedup vs baseline: 1.2401x; 1.1457x over previous
//
#include <hip/hip_runtime.h>
#include <math.h>

typedef __attribute__((ext_vector_type(4))) float f32x4;
typedef __attribute__((ext_vector_type(8))) _Float16 f16x8;

__device__ __forceinline__ f32x4 mfma16h(f16x8 a, f16x8 b, f32x4 c){
  return __builtin_amdgcn_mfma_f32_16x16x32_f16(a, b, c, 0, 0, 0);
}
__device__ __forceinline__ void gload_lds16(const void* g, void* l){
  __builtin_amdgcn_global_load_lds((const __attribute__((address_space(1))) void*)g,
                                   (__attribute__((address_space(3))) void*)l, 16, 0, 0);
}

#define EXPC 0.1803368801111204f   // 0.125 * log2(e)

// ---------------- weight stats: alpha=mean(w), beta-sum=sum|w| ----------------
__global__ __launch_bounds__(256) void k_wstats(const float* __restrict__ w1, const float* __restrict__ w2,
                                                double* __restrict__ dsum, double* __restrict__ dabs){
  const int mat = blockIdx.y;
  const float* wp = (mat < 6) ? (w1 + (size_t)mat*1048576) : (w2 + (size_t)(mat-6)*1048576);
  const f32x4* wv = (const f32x4*)wp + (size_t)blockIdx.x*8192;
  double s = 0.0, a = 0.0;
  for (int j = 0; j < 32; j++){
    f32x4 v = wv[j*256 + threadIdx.x];
    s += (double)v.x + (double)v.y + (double)v.z + (double)v.w;
    a += (double)fabsf(v.x) + (double)fabsf(v.y) + (double)fabsf(v.z) + (double)fabsf(v.w);
  }
  for (int d = 1; d < 64; d <<= 1){ s += __shfl_xor(s, d); a += __shfl_xor(a, d); }
  __shared__ double red[8];
  const int w = threadIdx.x >> 6;
  if ((threadIdx.x & 63) == 0){ red[w*2] = s; red[w*2+1] = a; }
  __syncthreads();
  if (threadIdx.x == 0){
    double S = red[0]+red[2]+red[4]+red[6], A = red[1]+red[3]+red[5]+red[7];
    atomicAdd(&dsum[mat], S);
    atomicAdd(&dabs[mat], A);
  }
}

// ---------------- binarize weights to fp16 {-1,0,+1}, swizzled GEMM-B layout ----------------
// layout: wb[mat][n][ (k&~63) + ((k&63) ^ 8*(n&7)) ]
__global__ __launch_bounds__(256) void k_binarize(const float* __restrict__ w1, const float* __restrict__ w2,
                                                  const double* __restrict__ dsum, _Float16* __restrict__ wb){
  const int blk = blockIdx.x;          // 6144 blocks, 512 per matrix
  const int mat = blk >> 9;
  const float alpha = (float)(dsum[mat] * (1.0/1048576.0));
  const float* wp = (mat < 6) ? (w1 + (size_t)mat*1048576) : (w2 + (size_t)(mat-6)*1048576);
  const size_t off = (size_t)(blk & 511)*2048 + (size_t)threadIdx.x*8;
  const int n = (int)(off >> 10), k = (int)(off & 1023);
  f32x4 v0 = *(const f32x4*)(wp + off), v1 = *(const f32x4*)(wp + off + 4);
  float vv[8] = {v0.x,v0.y,v0.z,v0.w,v1.x,v1.y,v1.z,v1.w};
  f16x8 pk;
  #pragma unroll
  for (int e = 0; e < 8; e++){
    float d = vv[e] - alpha;
    pk[e] = d > 0.f ? (_Float16)1.0f : (d < 0.f ? (_Float16)(-1.0f) : (_Float16)0.0f);
  }
  const size_t addr = (size_t)mat*1048576 + (size_t)n*1024 + (size_t)((k & ~63) + ((k & 63) ^ ((n&7)*8)));
  *(f16x8*)&wb[addr] = pk;
}

// ---------------- presplit: x (fp32) -> fp16 hi/lo in K-layout and V^T-layout ----------------
// K:  Kh/Kl[bh][n][ d ^ 8*phi(n&63) ]  with phi(m) = bits[4,3,0] of m (for attn's
//     permuted-K staging: the read-side XOR must vary with lane bits r3,r2,r0)
// VT: Vh/Vl[bh][d][ t*64 + ((n&63) ^ 8*(d&7)) ]
__global__ __launch_bounds__(256) void k_presplit(const float* __restrict__ x,
                                                  _Float16* __restrict__ Kh, _Float16* __restrict__ Kl,
                                                  _Float16* __restrict__ Vh, _Float16* __restrict__ Vl){
  __shared__ _Float16 lh[64*72], ll[64*72];
  const int t = blockIdx.x, bh = blockIdx.y, b = bh>>4, h = bh&15;
  const int n = threadIdx.x>>2, c0 = (threadIdx.x&3)*16;
  const float* src = x + (size_t)b*1048576 + (size_t)(t*64+n)*1024 + h*64 + c0;
  const size_t kbase = ((size_t)bh*1024 + t*64 + n)*64;
  const int sw = ((((n>>4)&1)<<2) | (((n>>3)&1)<<1) | (n&1)) * 8;   // phi(n)*8
  #pragma unroll
  for (int j = 0; j < 2; j++){
    f32x4 v0 = *(const f32x4*)(src + j*8);
    f32x4 v1 = *(const f32x4*)(src + j*8 + 4);
    float vv[8] = {v0.x,v0.y,v0.z,v0.w,v1.x,v1.y,v1.z,v1.w};
    f16x8 Hv, Lv;
    #pragma unroll
    for (int e = 0; e < 8; e++){
      _Float16 hh = (_Float16)vv[e];
      Hv[e] = hh; Lv[e] = (_Float16)(vv[e] - (float)hh);
      const int d = c0 + j*8 + e;
      lh[d*72 + n] = Hv[e]; ll[d*72 + n] = Lv[e];
    }
    const int db = c0 + j*8;
    *(f16x8*)&Kh[kbase + (db ^ sw)] = Hv;
    *(f16x8*)&Kl[kbase + (db ^ sw)] = Lv;
  }
  __syncthreads();
  const int d = threadIdx.x>>2, n0c = (threadIdx.x&3)*16;
  const size_t vbase = ((size_t)bh*64 + d)*1024 + t*64;
  const int sw2 = (d&7)*8;
  #pragma unroll
  for (int j = 0; j < 2; j++){
    f16x8 Hv, Lv;
    #pragma unroll
    for (int e = 0; e < 8; e++){
      Hv[e] = lh[d*72 + n0c + j*8 + e];
      Lv[e] = ll[d*72 + n0c + j*8 + e];
    }
    const int nb = n0c + j*8;
    *(f16x8*)&Vh[vbase + (nb ^ sw2)] = Hv;
    *(f16x8*)&Vl[vbase + (nb ^ sw2)] = Lv;
  }
}

// ---------------- flash attention + residual: swapped QK^T + permuted-K staging ----------------
// grid (32 bh, 16 qt), 256 thr. K rows staged into LDS position p holding actual key
// kappa(p) = [p5,p3,p2,p4,p1,p0] so that the swapped-QK^T output (lane r16,g holds
// scores for staged rows c*16+g*4+i) lands exactly on the PV A-frag keys
// ks*32+g*8+jj (ks=c>>1, jj=(c&1)*4+i). P never leaves the lane: no shuffles, no LDS.
__global__ __launch_bounds__(256) void k_attn(const _Float16* __restrict__ Kh, const _Float16* __restrict__ Kl,
                                              const _Float16* __restrict__ Vh, const _Float16* __restrict__ Vl,
                                              const float* __restrict__ xin, float* __restrict__ xout){
  __shared__ _Float16 smb[40960];   // 80 KB: 2 x 32KB {Kh,Kl,Vh,Vl} dbuf + 16KB Q stage
  _Float16* qs_h = smb + 32768;
  _Float16* qs_l = smb + 36864;
  const int tid = threadIdx.x, w = tid>>6, l = tid&63, g = l>>4, r16 = l&15;
  const int bh = blockIdx.x, qt = blockIdx.y, b = bh>>4, h = bh&15;
  const _Float16* Kbh = Kh + (size_t)bh*65536;
  const _Float16* Kbl = Kl + (size_t)bh*65536;

  // staging offsets (t-invariant): LDS row p <- global key row kappa(p)
  size_t koffK[2], voff[2];
  int cbj[2];
  #pragma unroll
  for (int j = 0; j < 2; j++){
    const int cb = (j*4 + w)*64, c = cb + l;
    const int p  = c>>3;
    const int kp = (p&32) | ((p&12)<<1) | ((p&16)>>2) | (p&3);   // kappa(p)
    cbj[j]   = cb;
    koffK[j] = (size_t)kp*64 + (size_t)(l&7)*8;
    voff[j]  = ((size_t)bh*64 + (c>>3))*1024 + (size_t)(c&7)*8;
  }
  #define ASTAGE(buf, t) { _Float16* Bp = smb + (buf)*16384;                         \
    _Pragma("unroll")                                                                 \
    for (int j = 0; j < 2; j++){                                                      \
      gload_lds16(Kbh + (size_t)(t)*4096 + koffK[j], Bp + cbj[j]*8);                  \
      gload_lds16(Kbl + (size_t)(t)*4096 + koffK[j], Bp + 4096 + cbj[j]*8);           \
      gload_lds16(Vh + voff[j] + (t)*64, Bp + 8192 + cbj[j]*8);                       \
      gload_lds16(Vl + voff[j] + (t)*64, Bp + 12288 + cbj[j]*8);                      \
    } }

  // prologue: stage Q (linear, unpermuted) + tile 0, one drain
  const _Float16* Qsh = Kbh + (size_t)qt*4096;
  const _Float16* Qsl = Kbl + (size_t)qt*4096;
  #pragma unroll
  for (int j = 0; j < 2; j++){
    const int cb = cbj[j];
    gload_lds16(Qsh + (size_t)(cb + l)*8, qs_h + cb*8);
    gload_lds16(Qsl + (size_t)(cb + l)*8, qs_l + cb*8);
  }
  ASTAGE(0, 0);
  __syncthreads();
  const int qrow = w*16 + r16;
  const int phq8 = (((w&1)<<2) | (((r16>>3)&1)<<1) | (r16&1)) * 8;   // phi(qrow)*8
  const int swk8 = ((((r16>>3)&1)<<2) | (((r16>>2)&1)<<1) | (r16&1)) * 8;  // phi(kappa(rk))*8
  const int swr8 = (r16&7)*8;
  const f16x8 aqh0 = *(const f16x8*)&qs_h[qrow*64 + ((g*8) ^ phq8)];
  const f16x8 aqh1 = *(const f16x8*)&qs_h[qrow*64 + ((32 + g*8) ^ phq8)];
  const f16x8 aql0 = *(const f16x8*)&qs_l[qrow*64 + ((g*8) ^ phq8)];
  const f16x8 aql1 = *(const f16x8*)&qs_l[qrow*64 + ((32 + g*8) ^ phq8)];
  float mI = -1e30f, lI = 0.f;
  f32x4 acc[4];
  #pragma unroll
  for (int i = 0; i < 4; i++) acc[i] = (f32x4){0.f,0.f,0.f,0.f};

  for (int t = 0; t < 16; t++){
    if (t < 15) ASTAGE((t+1)&1, t+1);          // prefetch next tile into other buffer
    const _Float16* kt_h = smb + (t&1)*16384;
    const _Float16* kt_l = kt_h + 4096;
    const _Float16* vt_h = kt_h + 8192;
    const _Float16* vt_l = kt_h + 12288;
    // swapped QK^T: A=K(staged rows), B=Q -> s[c][i] = S[staged row c*16+g*4+i][q=w*16+r16]
    f32x4 s[4];
    #pragma unroll
    for (int c = 0; c < 4; c++){
      const int rk = c*16 + r16;
      const f16x8 kh0 = *(const f16x8*)&kt_h[rk*64 + ((g*8) ^ swk8)];
      const f16x8 kh1 = *(const f16x8*)&kt_h[rk*64 + ((32+g*8) ^ swk8)];
      const f16x8 kl0 = *(const f16x8*)&kt_l[rk*64 + ((g*8) ^ swk8)];
      const f16x8 kl1 = *(const f16x8*)&kt_l[rk*64 + ((32+g*8) ^ swk8)];
      f32x4 z = (f32x4){0.f,0.f,0.f,0.f};
      z = mfma16h(kh0, aqh0, z);
      z = mfma16h(kh1, aqh1, z);
      z = mfma16h(kh0, aql0, z);
      z = mfma16h(kh1, aql1, z);
      z = mfma16h(kl0, aqh0, z);
      z = mfma16h(kl1, aqh1, z);
      s[c] = z;
    }
    // per-lane scalar online softmax (one q-row per lane), exp2 domain, defer-rescale
    float rmax = s[0][0];
    #pragma unroll
    for (int c = 0; c < 4; c++)
      #pragma unroll
      for (int i = 0; i < 4; i++) rmax = fmaxf(rmax, s[c][i]);
    rmax = fmaxf(rmax, __shfl_xor(rmax, 16));
    rmax = fmaxf(rmax, __shfl_xor(rmax, 32));
    if (__any(rmax - mI > 44.36f)){
      const float mn = fmaxf(mI, rmax);
      const float fac = exp2f((mI - mn)*EXPC);
      lI *= fac;
      mI = mn;
      #pragma unroll
      for (int i = 0; i < 4; i++){
        const float fi = __shfl(fac, g*4 + i);
        #pragma unroll
        for (int dc = 0; dc < 4; dc++) acc[dc][i] *= fi;
      }
    }
    const float mC = mI*EXPC;
    float rsum = 0.f;
    f16x8 aph[2], apl[2];
    #pragma unroll
    for (int c = 0; c < 4; c++)
      #pragma unroll
      for (int i = 0; i < 4; i++){
        const float p = exp2f(fmaf(s[c][i], EXPC, -mC));
        const _Float16 ph = (_Float16)p;
        aph[c>>1][(c&1)*4 + i] = ph;
        apl[c>>1][(c&1)*4 + i] = (_Float16)(p - (float)ph);
        rsum += p;
      }
    rsum += __shfl_xor(rsum, 16);
    rsum += __shfl_xor(rsum, 32);
    lI += rsum;
    // PV: A = in-lane P (keys ks*32+g*8..+7 by construction), 3-term split
    #pragma unroll
    for (int ks = 0; ks < 2; ks++){
      #pragma unroll
      for (int dc = 0; dc < 4; dc++){
        const int vr = dc*16 + r16;
        const f16x8 bvh = *(const f16x8*)&vt_h[vr*64 + ((ks*32 + g*8) ^ swr8)];
        const f16x8 bvl = *(const f16x8*)&vt_l[vr*64 + ((ks*32 + g*8) ^ swr8)];
        acc[dc] = mfma16h(aph[ks], bvh, acc[dc]);
        acc[dc] = mfma16h(apl[ks], bvh, acc[dc]);
        acc[dc] = mfma16h(aph[ks], bvl, acc[dc]);
      }
    }
    __syncthreads();   // drains vmcnt: next buffer staged; all waves done with buf t&1
  }
  #undef ASTAGE
  #pragma unroll
  for (int i = 0; i < 4; i++){
    const float li = __shfl(lI, g*4 + i);
    const float inv = 1.f/li;
    const int row = qt*64 + w*16 + g*4 + i;
    #pragma unroll
    for (int dc = 0; dc < 4; dc++){
      const size_t idx = (size_t)b*1048576 + (size_t)row*1024 + h*64 + dc*16 + r16;
      xout[idx] = acc[dc][i]*inv + xin[idx];
    }
  }
}

// ---------------- layernorm; SPLIT=1 writes fp16 hi/lo in swizzled A-layout ----------------
template<int SPLIT>
__global__ __launch_bounds__(256) void k_ln(const float* __restrict__ x, const float* __restrict__ gg,
                                            const float* __restrict__ bb, float* __restrict__ outf,
                                            _Float16* __restrict__ Oh, _Float16* __restrict__ Ol){
  const int row = blockIdx.x*4 + (threadIdx.x>>6);
  const int lane = threadIdx.x & 63;
  const float* xr = x + (size_t)row*1024;
  f32x4 v[4];
  float s = 0.f, q = 0.f;
  #pragma unroll
  for (int c = 0; c < 2; c++){
    v[c*2]   = *(const f32x4*)(xr + c*512 + lane*8);
    v[c*2+1] = *(const f32x4*)(xr + c*512 + lane*8 + 4);
    #pragma unroll
    for (int e = 0; e < 4; e++){
      s += v[c*2][e] + v[c*2+1][e];
      q += v[c*2][e]*v[c*2][e] + v[c*2+1][e]*v[c*2+1][e];
    }
  }
  for (int d = 1; d < 64; d <<= 1){ s += __shfl_xor(s,d); q += __shfl_xor(q,d); }
  const float mean = s * (1.f/1024.f);
  const float var  = q * (1.f/1024.f) - mean*mean;
  const float rstd = rsqrtf(var + 1e-5f);
  #pragma unroll
  for (int c = 0; c < 2; c++){
    const int col = c*512 + lane*8;
    f32x4 g0 = *(const f32x4*)(gg + col), g1 = *(const f32x4*)(gg + col + 4);
    f32x4 b0 = *(const f32x4*)(bb + col), b1 = *(const f32x4*)(bb + col + 4);
    float h[8];
    #pragma unroll
    for (int e = 0; e < 4; e++){
      h[e]   = (v[c*2][e]  -mean)*rstd*g0[e] + b0[e];
      h[e+4] = (v[c*2+1][e]-mean)*rstd*g1[e] + b1[e];
    }
    if (SPLIT){
      f16x8 Hv, Lv;
      #pragma unroll
      for (int e = 0; e < 8; e++){
        _Float16 hh = (_Float16)h[e];
        Hv[e] = hh; Lv[e] = (_Float16)(h[e] - (float)hh);
      }
      const size_t addr = (size_t)row*1024 + c*512 + (lane>>3)*64 + (((lane&7)*8) ^ ((row&7)*8));
      *(f16x8*)&Oh[addr] = Hv;
      *(f16x8*)&Ol[addr] = Lv;
    } else {
      f32x4 o0, o1;
      #pragma unroll
      for (int e = 0; e < 4; e++){ o0[e] = h[e]; o1[e] = h[e+4]; }
      *(f32x4*)(outf + (size_t)row*1024 + col) = o0;
      *(f32x4*)(outf + (size_t)row*1024 + col + 4) = o1;
    }
  }
}

// ---------------- bitlinear GEMM: C[2048,1024] = (Ah+Al).Wb^T * beta ----------------
// BM=BN=64, BK=64, 4 waves (2Mx2N, wave-tile 32x32), double-buffered gload staging.
// MODE 0: GELU -> split fp16 out (swizzled A-layout). MODE 1: += into fp32 residual.
template<int MODE>
__global__ __launch_bounds__(256) void k_gemm(const _Float16* __restrict__ Ah, const _Float16* __restrict__ Al,
                                              const _Float16* __restrict__ Wg,
                                              float* __restrict__ out32,
                                              _Float16* __restrict__ Oh, _Float16* __restrict__ Ol,
                                              const double* __restrict__ dabs_slot){
  __shared__ _Float16 smb[24576];   // 2 x (A-hi 4096 + A-lo 4096 + B 4096)
  const int tid = threadIdx.x, w = tid>>6, l = tid&63, g = l>>4, r16 = l&15;
  const int wm = w>>1, wn = w&1;
  const int n0 = blockIdx.x*64, m0 = blockIdx.y*64;
  const float scale = (float)(*dabs_slot * (1.0/1048576.0));
  const int swr = (r16&7)*8;
  f32x4 acc[2][2] = {};
  #define STAGE(buf, k0) { _Float16* Bp = smb + (buf)*12288;                              \
    _Pragma("unroll")                                                                     \
    for (int j = 0; j < 2; j++){                                                          \
      const int cb = (j*4 + w)*64; const int c = cb + l;                                  \
      const int r = c>>3; const int cc = (c&7)*8;                                         \
      gload_lds16(Ah + (size_t)(m0 + r)*1024 + (k0) + cc, Bp + cb*8);                     \
      gload_lds16(Al + (size_t)(m0 + r)*1024 + (k0) + cc, Bp + 4096 + cb*8);              \
      gload_lds16(Wg + (size_t)(n0 + r)*1024 + (k0) + cc, Bp + 8192 + cb*8);              \
    } }
  STAGE(0, 0);
  __syncthreads();
  for (int t = 0; t < 16; t++){
    if (t < 15) STAGE((t+1)&1, (t+1)*64);
    const _Float16* Bp = smb + (t&1)*12288;
    #pragma unroll
    for (int kk = 0; kk < 2; kk++){
      f16x8 ah[2], al[2], bf[2];
      const int col = (kk*32 + g*8) ^ swr;
      #pragma unroll
      for (int mi = 0; mi < 2; mi++){
        const int row = wm*32 + mi*16 + r16;
        ah[mi] = *(const f16x8*)&Bp[row*64 + col];
        al[mi] = *(const f16x8*)&Bp[4096 + row*64 + col];
      }
      #pragma unroll
      for (int ni = 0; ni < 2; ni++){
        const int row = wn*32 + ni*16 + r16;
        bf[ni] = *(const f16x8*)&Bp[8192 + row*64 + col];
      }
      #pragma unroll
      for (int mi = 0; mi < 2; mi++)
        #pragma unroll
        for (int ni = 0; ni < 2; ni++){
          acc[mi][ni] = mfma16h(ah[mi], bf[ni], acc[mi][ni]);
          acc[mi][ni] = mfma16h(al[mi], bf[ni], acc[mi][ni]);
        }
    }
    __syncthreads();
  }
  #undef STAGE
  #pragma unroll
  for (int mi = 0; mi < 2; mi++)
    #pragma unroll
    for (int ni = 0; ni < 2; ni++)
      #pragma unroll
      for (int i = 0; i < 4; i++){
        const int rr = m0 + wm*32 + mi*16 + g*4 + i;
        const int cc = n0 + wn*32 + ni*16 + r16;
        float vv = acc[mi][ni][i] * scale;
        if (MODE == 0){
          vv = 0.5f*vv*(1.f + erff(vv*0.70710678118f));
          _Float16 hh = (_Float16)vv;
          const size_t addr = (size_t)rr*1024 + (cc & ~63) + ((cc & 63) ^ ((rr&7)*8));
          Oh[addr] = hh;
          Ol[addr] = (_Float16)(vv - (float)hh);
        } else {
          out32[(size_t)rr*1024 + cc] += vv;
        }
      }
}

extern "C" void kernel_launch(void* const* d_in, const int* in_sizes, int n_in,
                              void* d_out, int out_size, void* d_ws, size_t ws_size,
                              hipStream_t stream){
  const float* x_in = (const float*)d_in[0];
  const float* ln_g = (const float*)d_in[1];
  const float* ln_b = (const float*)d_in[2];
  const float* w1   = (const float*)d_in[3];
  const float* w2   = (const float*)d_in[4];
  const float* fg   = (const float*)d_in[5];
  const float* fb   = (const float*)d_in[6];

  char* ws = (char*)d_ws;
  double*   dsum  = (double*)ws;            // 12
  double*   dabs  = (double*)(ws + 96);     // 12
  _Float16* wb = (_Float16*)(ws + 256);     // 12 * 1M fp16 = 24 MB
  size_t o = 256 + 12ull*1048576ull*2ull;
  float* xA = (float*)(ws + o); o += 2048ull*1024*4;
  float* xB = (float*)(ws + o); o += 2048ull*1024*4;
  _Float16* Kh = (_Float16*)(ws + o); o += 2048ull*1024*2;
  _Float16* Kl = (_Float16*)(ws + o); o += 2048ull*1024*2;
  _Float16* Vh = (_Float16*)(ws + o); o += 2048ull*1024*2;
  _Float16* Vl = (_Float16*)(ws + o); o += 2048ull*1024*2;
  _Float16* Ahb = (_Float16*)(ws + o); o += 2048ull*1024*2;
  _Float16* Alb = (_Float16*)(ws + o); o += 2048ull*1024*2;
  _Float16* Ghb = (_Float16*)(ws + o); o += 2048ull*1024*2;
  _Float16* Glb = (_Float16*)(ws + o); o += 2048ull*1024*2;

  hipMemsetAsync(ws, 0, 256, stream);
  k_wstats  <<<dim3(32,12), 256, 0, stream>>>(w1, w2, dsum, dabs);
  k_binarize<<<6144,        256, 0, stream>>>(w1, w2, dsum, wb);

  const float* xc = x_in;
  for (int i = 0; i < 6; i++){
    float* xn = (i & 1) ? xB : xA;
    k_presplit<<<dim3(16,32), 256, 0, stream>>>(xc, Kh, Kl, Vh, Vl);
    k_attn    <<<dim3(32,16), 256, 0, stream>>>(Kh, Kl, Vh, Vl, xc, xn);
    k_ln<1>   <<<512, 256, 0, stream>>>(xn, ln_g + (size_t)i*1024, ln_b + (size_t)i*1024,
                                        nullptr, Ahb, Alb);
    k_gemm<0> <<<dim3(16,32), 256, 0, stream>>>(Ahb, Alb, wb + (size_t)i*1048576,
                                                nullptr, Ghb, Glb, &dabs[i]);
    k_gemm<1> <<<dim3(16,32), 256, 0, stream>>>(Ghb, Glb, wb + (size_t)(6+i)*1048576,
                                                xn, nullptr, nullptr, &dabs[6+i]);
    xc = xn;
  }
  k_ln<0><<<512, 256, 0, stream>>>(xc, fg, fb, (float*)d_out, nullptr, nullptr);
}

// Round 10
// 512.778 us; speedup vs baseline: 1.2587x; 1.0150x over previous
//
#include <hip/hip_runtime.h>
#include <math.h>

typedef __attribute__((ext_vector_type(4))) float f32x4;
typedef __attribute__((ext_vector_type(8))) _Float16 f16x8;

__device__ __forceinline__ f32x4 mfma16h(f16x8 a, f16x8 b, f32x4 c){
  return __builtin_amdgcn_mfma_f32_16x16x32_f16(a, b, c, 0, 0, 0);
}
__device__ __forceinline__ void gload_lds16(const void* g, void* l){
  __builtin_amdgcn_global_load_lds((const __attribute__((address_space(1))) void*)g,
                                   (__attribute__((address_space(3))) void*)l, 16, 0, 0);
}

#define EXPC 0.1803368801111204f   // 0.125 * log2(e)
// global K swizzle phi(n) = bits (n3,n1,n0): chosen so phi(kappa(p)) = p&7 ->
// attn K-read XOR is (r16&7)*8, sequential across lanes = conflict-free (r7-verified).
#define PHI(n) (((((n)>>3)&1)<<2) | ((((n)>>1)&1)<<1) | ((n)&1))

// ---------------- weight stats: alpha=mean(w), beta-sum=sum|w| ----------------
__global__ __launch_bounds__(256) void k_wstats(const float* __restrict__ w1, const float* __restrict__ w2,
                                                double* __restrict__ dsum, double* __restrict__ dabs){
  const int mat = blockIdx.y;
  const float* wp = (mat < 6) ? (w1 + (size_t)mat*1048576) : (w2 + (size_t)(mat-6)*1048576);
  const f32x4* wv = (const f32x4*)wp + (size_t)blockIdx.x*8192;
  double s = 0.0, a = 0.0;
  for (int j = 0; j < 32; j++){
    f32x4 v = wv[j*256 + threadIdx.x];
    s += (double)v.x + (double)v.y + (double)v.z + (double)v.w;
    a += (double)fabsf(v.x) + (double)fabsf(v.y) + (double)fabsf(v.z) + (double)fabsf(v.w);
  }
  for (int d = 1; d < 64; d <<= 1){ s += __shfl_xor(s, d); a += __shfl_xor(a, d); }
  __shared__ double red[8];
  const int w = threadIdx.x >> 6;
  if ((threadIdx.x & 63) == 0){ red[w*2] = s; red[w*2+1] = a; }
  __syncthreads();
  if (threadIdx.x == 0){
    double S = red[0]+red[2]+red[4]+red[6], A = red[1]+red[3]+red[5]+red[7];
    atomicAdd(&dsum[mat], S);
    atomicAdd(&dabs[mat], A);
  }
}

// ---------------- binarize weights to fp16 {-1,0,+1}, swizzled GEMM-B layout ----------------
// layout: wb[mat][n][ (k&~63) + ((k&63) ^ 8*(n&7)) ]
__global__ __launch_bounds__(256) void k_binarize(const float* __restrict__ w1, const float* __restrict__ w2,
                                                  const double* __restrict__ dsum, _Float16* __restrict__ wb){
  const int blk = blockIdx.x;          // 6144 blocks, 512 per matrix
  const int mat = blk >> 9;
  const float alpha = (float)(dsum[mat] * (1.0/1048576.0));
  const float* wp = (mat < 6) ? (w1 + (size_t)mat*1048576) : (w2 + (size_t)(mat-6)*1048576);
  const size_t off = (size_t)(blk & 511)*2048 + (size_t)threadIdx.x*8;
  const int n = (int)(off >> 10), k = (int)(off & 1023);
  f32x4 v0 = *(const f32x4*)(wp + off), v1 = *(const f32x4*)(wp + off + 4);
  float vv[8] = {v0.x,v0.y,v0.z,v0.w,v1.x,v1.y,v1.z,v1.w};
  f16x8 pk;
  #pragma unroll
  for (int e = 0; e < 8; e++){
    float d = vv[e] - alpha;
    pk[e] = d > 0.f ? (_Float16)1.0f : (d < 0.f ? (_Float16)(-1.0f) : (_Float16)0.0f);
  }
  const size_t addr = (size_t)mat*1048576 + (size_t)n*1024 + (size_t)((k & ~63) + ((k & 63) ^ ((n&7)*8)));
  *(f16x8*)&wb[addr] = pk;
}

// ---------------- presplit (layer 0 only): x -> fp16 hi/lo K-layout + V^T-layout ----------------
// K:  Kh/Kl[bh][n][ d ^ 8*PHI(n&63) ]
// VT: Vh/Vl[bh][d][ t*64 + ((n&63) ^ 8*(d&7)) ]
__global__ __launch_bounds__(256) void k_presplit(const float* __restrict__ x,
                                                  _Float16* __restrict__ Kh, _Float16* __restrict__ Kl,
                                                  _Float16* __restrict__ Vh, _Float16* __restrict__ Vl){
  __shared__ _Float16 lh[64*72], ll[64*72];
  const int t = blockIdx.x, bh = blockIdx.y, b = bh>>4, h = bh&15;
  const int n = threadIdx.x>>2, c0 = (threadIdx.x&3)*16;
  const float* src = x + (size_t)b*1048576 + (size_t)(t*64+n)*1024 + h*64 + c0;
  const size_t kbase = ((size_t)bh*1024 + t*64 + n)*64;
  const int sw = PHI(n)*8;
  #pragma unroll
  for (int j = 0; j < 2; j++){
    f32x4 v0 = *(const f32x4*)(src + j*8);
    f32x4 v1 = *(const f32x4*)(src + j*8 + 4);
    float vv[8] = {v0.x,v0.y,v0.z,v0.w,v1.x,v1.y,v1.z,v1.w};
    f16x8 Hv, Lv;
    #pragma unroll
    for (int e = 0; e < 8; e++){
      _Float16 hh = (_Float16)vv[e];
      Hv[e] = hh; Lv[e] = (_Float16)(vv[e] - (float)hh);
      const int d = c0 + j*8 + e;
      lh[d*72 + n] = Hv[e]; ll[d*72 + n] = Lv[e];
    }
    const int db = c0 + j*8;
    *(f16x8*)&Kh[kbase + (db ^ sw)] = Hv;
    *(f16x8*)&Kl[kbase + (db ^ sw)] = Lv;
  }
  __syncthreads();
  const int d = threadIdx.x>>2, n0c = (threadIdx.x&3)*16;
  const size_t vbase = ((size_t)bh*64 + d)*1024 + t*64;
  const int sw2 = (d&7)*8;
  #pragma unroll
  for (int j = 0; j < 2; j++){
    const int nb = n0c + j*8;
    *(f16x8*)&Vh[vbase + (nb ^ sw2)] = *(const f16x8*)&lh[d*72 + nb];
    *(f16x8*)&Vl[vbase + (nb ^ sw2)] = *(const f16x8*)&ll[d*72 + nb];
  }
}

// ---------------- flash attention + residual: swapped QK^T + permuted-K staging ----------------
// grid (32 bh, 16 qt), 256 thr. K rows staged into LDS position p holding actual key
// kappa(p) = [p5,p3,p2,p4,p1,p0] so the swapped-QK^T output lands directly on the PV
// A-frag keys (P never leaves the lane). Read-side XOR = (r16&7)*8 via PHI choice.
__global__ __launch_bounds__(256) void k_attn(const _Float16* __restrict__ Kh, const _Float16* __restrict__ Kl,
                                              const _Float16* __restrict__ Vh, const _Float16* __restrict__ Vl,
                                              const float* __restrict__ xin, float* __restrict__ xout){
  __shared__ _Float16 smb[40960];   // 80 KB: 2 x 32KB {Kh,Kl,Vh,Vl} dbuf + 16KB Q stage
  _Float16* qs_h = smb + 32768;
  _Float16* qs_l = smb + 36864;
  const int tid = threadIdx.x, w = tid>>6, l = tid&63, g = l>>4, r16 = l&15;
  const int bh = blockIdx.x, qt = blockIdx.y, b = bh>>4, h = bh&15;
  const _Float16* Kbh = Kh + (size_t)bh*65536;
  const _Float16* Kbl = Kl + (size_t)bh*65536;

  // staging offsets (t-invariant): LDS row p <- global key row kappa(p)
  size_t koffK[2], voff[2];
  int cbj[2];
  #pragma unroll
  for (int j = 0; j < 2; j++){
    const int cb = (j*4 + w)*64, c = cb + l;
    const int p  = c>>3;
    const int kp = (p&32) | ((p&12)<<1) | ((p&16)>>2) | (p&3);   // kappa(p)
    cbj[j]   = cb;
    koffK[j] = (size_t)kp*64 + (size_t)(l&7)*8;
    voff[j]  = ((size_t)bh*64 + (c>>3))*1024 + (size_t)(c&7)*8;
  }
  #define ASTAGE(buf, t) { _Float16* Bp = smb + (buf)*16384;                         \
    _Pragma("unroll")                                                                 \
    for (int j = 0; j < 2; j++){                                                      \
      gload_lds16(Kbh + (size_t)(t)*4096 + koffK[j], Bp + cbj[j]*8);                  \
      gload_lds16(Kbl + (size_t)(t)*4096 + koffK[j], Bp + 4096 + cbj[j]*8);           \
      gload_lds16(Vh + voff[j] + (t)*64, Bp + 8192 + cbj[j]*8);                       \
      gload_lds16(Vl + voff[j] + (t)*64, Bp + 12288 + cbj[j]*8);                      \
    } }

  // prologue: stage Q (linear, unpermuted) + tile 0, one drain
  const _Float16* Qsh = Kbh + (size_t)qt*4096;
  const _Float16* Qsl = Kbl + (size_t)qt*4096;
  #pragma unroll
  for (int j = 0; j < 2; j++){
    const int cb = cbj[j];
    gload_lds16(Qsh + (size_t)(cb + l)*8, qs_h + cb*8);
    gload_lds16(Qsl + (size_t)(cb + l)*8, qs_l + cb*8);
  }
  ASTAGE(0, 0);
  __syncthreads();
  const int qrow = w*16 + r16;
  const int phq8 = PHI(qrow)*8;            // Q-read XOR (once per block, ~2-way max)
  const int swk8 = (r16&7)*8;              // K-read XOR = phi(kappa(rk)) by construction
  const int swr8 = (r16&7)*8;              // V-read XOR
  const f16x8 aqh0 = *(const f16x8*)&qs_h[qrow*64 + ((g*8) ^ phq8)];
  const f16x8 aqh1 = *(const f16x8*)&qs_h[qrow*64 + ((32 + g*8) ^ phq8)];
  const f16x8 aql0 = *(const f16x8*)&qs_l[qrow*64 + ((g*8) ^ phq8)];
  const f16x8 aql1 = *(const f16x8*)&qs_l[qrow*64 + ((32 + g*8) ^ phq8)];
  float mI = -1e30f, lI = 0.f;
  f32x4 acc[4];
  #pragma unroll
  for (int i = 0; i < 4; i++) acc[i] = (f32x4){0.f,0.f,0.f,0.f};

  for (int t = 0; t < 16; t++){
    if (t < 15) ASTAGE((t+1)&1, t+1);          // prefetch next tile into other buffer
    const _Float16* kt_h = smb + (t&1)*16384;
    const _Float16* kt_l = kt_h + 4096;
    const _Float16* vt_h = kt_h + 8192;
    const _Float16* vt_l = kt_h + 12288;
    // swapped QK^T: A=K(staged rows), B=Q -> s[c][i] = S[staged row c*16+g*4+i][q]
    f32x4 s[4];
    #pragma unroll
    for (int c = 0; c < 4; c++){
      const int rk = c*16 + r16;
      const f16x8 kh0 = *(const f16x8*)&kt_h[rk*64 + ((g*8) ^ swk8)];
      const f16x8 kh1 = *(const f16x8*)&kt_h[rk*64 + ((32+g*8) ^ swk8)];
      const f16x8 kl0 = *(const f16x8*)&kt_l[rk*64 + ((g*8) ^ swk8)];
      const f16x8 kl1 = *(const f16x8*)&kt_l[rk*64 + ((32+g*8) ^ swk8)];
      f32x4 z = (f32x4){0.f,0.f,0.f,0.f};
      z = mfma16h(kh0, aqh0, z);
      z = mfma16h(kh1, aqh1, z);
      z = mfma16h(kh0, aql0, z);
      z = mfma16h(kh1, aql1, z);
      z = mfma16h(kl0, aqh0, z);
      z = mfma16h(kl1, aqh1, z);
      s[c] = z;
    }
    // per-lane scalar online softmax (one q-row per lane), exp2 domain, defer-rescale
    float rmax = s[0][0];
    #pragma unroll
    for (int c = 0; c < 4; c++)
      #pragma unroll
      for (int i = 0; i < 4; i++) rmax = fmaxf(rmax, s[c][i]);
    rmax = fmaxf(rmax, __shfl_xor(rmax, 16));
    rmax = fmaxf(rmax, __shfl_xor(rmax, 32));
    if (__any(rmax - mI > 44.36f)){
      const float mn = fmaxf(mI, rmax);
      const float fac = exp2f((mI - mn)*EXPC);
      lI *= fac;
      mI = mn;
      #pragma unroll
      for (int i = 0; i < 4; i++){
        const float fi = __shfl(fac, g*4 + i);
        #pragma unroll
        for (int dc = 0; dc < 4; dc++) acc[dc][i] *= fi;
      }
    }
    const float mC = mI*EXPC;
    float rsum = 0.f;
    f16x8 aph[2], apl[2];
    #pragma unroll
    for (int c = 0; c < 4; c++)
      #pragma unroll
      for (int i = 0; i < 4; i++){
        const float p = exp2f(fmaf(s[c][i], EXPC, -mC));
        const _Float16 ph = (_Float16)p;
        aph[c>>1][(c&1)*4 + i] = ph;
        apl[c>>1][(c&1)*4 + i] = (_Float16)(p - (float)ph);
        rsum += p;
      }
    rsum += __shfl_xor(rsum, 16);
    rsum += __shfl_xor(rsum, 32);
    lI += rsum;
    // PV: A = in-lane P (keys ks*32+g*8..+7 by construction), 3-term split
    #pragma unroll
    for (int ks = 0; ks < 2; ks++){
      #pragma unroll
      for (int dc = 0; dc < 4; dc++){
        const int vr = dc*16 + r16;
        const f16x8 bvh = *(const f16x8*)&vt_h[vr*64 + ((ks*32 + g*8) ^ swr8)];
        const f16x8 bvl = *(const f16x8*)&vt_l[vr*64 + ((ks*32 + g*8) ^ swr8)];
        acc[dc] = mfma16h(aph[ks], bvh, acc[dc]);
        acc[dc] = mfma16h(apl[ks], bvh, acc[dc]);
        acc[dc] = mfma16h(aph[ks], bvl, acc[dc]);
      }
    }
    __syncthreads();   // drains vmcnt: next buffer staged; all waves done with buf t&1
  }
  #undef ASTAGE
  #pragma unroll
  for (int i = 0; i < 4; i++){
    const float li = __shfl(lI, g*4 + i);
    const float inv = 1.f/li;
    const int row = qt*64 + w*16 + g*4 + i;
    #pragma unroll
    for (int dc = 0; dc < 4; dc++){
      const size_t idx = (size_t)b*1048576 + (size_t)row*1024 + h*64 + dc*16 + r16;
      xout[idx] = acc[dc][i]*inv + xin[idx];
    }
  }
}

// ---------------- layernorm; SPLIT=1 writes fp16 hi/lo in swizzled A-layout ----------------
template<int SPLIT>
__global__ __launch_bounds__(256) void k_ln(const float* __restrict__ x, const float* __restrict__ gg,
                                            const float* __restrict__ bb, float* __restrict__ outf,
                                            _Float16* __restrict__ Oh, _Float16* __restrict__ Ol){
  const int row = blockIdx.x*4 + (threadIdx.x>>6);
  const int lane = threadIdx.x & 63;
  const float* xr = x + (size_t)row*1024;
  f32x4 v[4];
  float s = 0.f, q = 0.f;
  #pragma unroll
  for (int c = 0; c < 2; c++){
    v[c*2]   = *(const f32x4*)(xr + c*512 + lane*8);
    v[c*2+1] = *(const f32x4*)(xr + c*512 + lane*8 + 4);
    #pragma unroll
    for (int e = 0; e < 4; e++){
      s += v[c*2][e] + v[c*2+1][e];
      q += v[c*2][e]*v[c*2][e] + v[c*2+1][e]*v[c*2+1][e];
    }
  }
  for (int d = 1; d < 64; d <<= 1){ s += __shfl_xor(s,d); q += __shfl_xor(q,d); }
  const float mean = s * (1.f/1024.f);
  const float var  = q * (1.f/1024.f) - mean*mean;
  const float rstd = rsqrtf(var + 1e-5f);
  #pragma unroll
  for (int c = 0; c < 2; c++){
    const int col = c*512 + lane*8;
    f32x4 g0 = *(const f32x4*)(gg + col), g1 = *(const f32x4*)(gg + col + 4);
    f32x4 b0 = *(const f32x4*)(bb + col), b1 = *(const f32x4*)(bb + col + 4);
    float h[8];
    #pragma unroll
    for (int e = 0; e < 4; e++){
      h[e]   = (v[c*2][e]  -mean)*rstd*g0[e] + b0[e];
      h[e+4] = (v[c*2+1][e]-mean)*rstd*g1[e] + b1[e];
    }
    if (SPLIT){
      f16x8 Hv, Lv;
      #pragma unroll
      for (int e = 0; e < 8; e++){
        _Float16 hh = (_Float16)h[e];
        Hv[e] = hh; Lv[e] = (_Float16)(h[e] - (float)hh);
      }
      const size_t addr = (size_t)row*1024 + c*512 + (lane>>3)*64 + (((lane&7)*8) ^ ((row&7)*8));
      *(f16x8*)&Oh[addr] = Hv;
      *(f16x8*)&Ol[addr] = Lv;
    } else {
      f32x4 o0, o1;
      #pragma unroll
      for (int e = 0; e < 4; e++){ o0[e] = h[e]; o1[e] = h[e+4]; }
      *(f32x4*)(outf + (size_t)row*1024 + col) = o0;
      *(f32x4*)(outf + (size_t)row*1024 + col + 4) = o1;
    }
  }
}

// ---------------- bitlinear GEMM: C[2048,1024] = (Ah+Al).Wb^T * beta ----------------
// BM=BN=64, BK=64, 4 waves (2Mx2N, wave-tile 32x32), double-buffered gload staging.
// MODE 0: GELU -> split fp16 out (swizzled A-layout).
// MODE 1: += into fp32 residual; if Kh!=null, ALSO produce next layer's K/V split
//         layouts (fused presplit: this block == presplit unit t=by&15, bh=(by>>4)*16+bx).
template<int MODE>
__global__ __launch_bounds__(256) void k_gemm(const _Float16* __restrict__ Ah, const _Float16* __restrict__ Al,
                                              const _Float16* __restrict__ Wg,
                                              float* __restrict__ out32,
                                              _Float16* __restrict__ Oh, _Float16* __restrict__ Ol,
                                              const double* __restrict__ dabs_slot,
                                              _Float16* __restrict__ Kh, _Float16* __restrict__ Kl,
                                              _Float16* __restrict__ Vh, _Float16* __restrict__ Vl){
  __shared__ _Float16 smb[24576];   // 2 x (A-hi 4096 + A-lo 4096 + B 4096); reused post-loop
  const int tid = threadIdx.x, w = tid>>6, l = tid&63, g = l>>4, r16 = l&15;
  const int wm = w>>1, wn = w&1;
  const int n0 = blockIdx.x*64, m0 = blockIdx.y*64;
  const float scale = (float)(*dabs_slot * (1.0/1048576.0));
  const int swr = (r16&7)*8;
  f32x4 acc[2][2] = {};
  #define STAGE(buf, k0) { _Float16* Bp = smb + (buf)*12288;                              \
    _Pragma("unroll")                                                                     \
    for (int j = 0; j < 2; j++){                                                          \
      const int cb = (j*4 + w)*64; const int c = cb + l;                                  \
      const int r = c>>3; const int cc = (c&7)*8;                                         \
      gload_lds16(Ah + (size_t)(m0 + r)*1024 + (k0) + cc, Bp + cb*8);                     \
      gload_lds16(Al + (size_t)(m0 + r)*1024 + (k0) + cc, Bp + 4096 + cb*8);              \
      gload_lds16(Wg + (size_t)(n0 + r)*1024 + (k0) + cc, Bp + 8192 + cb*8);              \
    } }
  STAGE(0, 0);
  __syncthreads();
  for (int t = 0; t < 16; t++){
    if (t < 15) STAGE((t+1)&1, (t+1)*64);
    const _Float16* Bp = smb + (t&1)*12288;
    #pragma unroll
    for (int kk = 0; kk < 2; kk++){
      f16x8 ah[2], al[2], bf[2];
      const int col = (kk*32 + g*8) ^ swr;
      #pragma unroll
      for (int mi = 0; mi < 2; mi++){
        const int row = wm*32 + mi*16 + r16;
        ah[mi] = *(const f16x8*)&Bp[row*64 + col];
        al[mi] = *(const f16x8*)&Bp[4096 + row*64 + col];
      }
      #pragma unroll
      for (int ni = 0; ni < 2; ni++){
        const int row = wn*32 + ni*16 + r16;
        bf[ni] = *(const f16x8*)&Bp[8192 + row*64 + col];
      }
      #pragma unroll
      for (int mi = 0; mi < 2; mi++)
        #pragma unroll
        for (int ni = 0; ni < 2; ni++){
          acc[mi][ni] = mfma16h(ah[mi], bf[ni], acc[mi][ni]);
          acc[mi][ni] = mfma16h(al[mi], bf[ni], acc[mi][ni]);
        }
    }
    __syncthreads();
  }
  #undef STAGE
  // post-loop LDS reuse (all waves past final barrier): split-tile staging for fused KV
  _Float16* kh_t = smb;            // [64][72] token-major hi
  _Float16* kl_t = smb + 4608;     // [64][72] token-major lo
  _Float16* lhv  = smb + 9216;     // [64][72] d-major hi
  _Float16* llv  = smb + 13824;    // [64][72] d-major lo
  #pragma unroll
  for (int mi = 0; mi < 2; mi++)
    #pragma unroll
    for (int ni = 0; ni < 2; ni++)
      #pragma unroll
      for (int i = 0; i < 4; i++){
        const int rr = m0 + wm*32 + mi*16 + g*4 + i;
        const int cc = n0 + wn*32 + ni*16 + r16;
        float vv = acc[mi][ni][i] * scale;
        if (MODE == 0){
          vv = 0.5f*vv*(1.f + erff(vv*0.70710678118f));
          _Float16 hh = (_Float16)vv;
          const size_t addr = (size_t)rr*1024 + (cc & ~63) + ((cc & 63) ^ ((rr&7)*8));
          Oh[addr] = hh;
          Ol[addr] = (_Float16)(vv - (float)hh);
        } else {
          const size_t idx = (size_t)rr*1024 + cc;
          const float xnew = out32[idx] + vv;
          out32[idx] = xnew;
          if (Kh){
            const int nl = wm*32 + mi*16 + g*4 + i;   // token within tile
            const int dl = wn*32 + ni*16 + r16;       // d within head
            const _Float16 hh = (_Float16)xnew;
            const _Float16 lo = (_Float16)(xnew - (float)hh);
            kh_t[nl*72 + dl] = hh;  kl_t[nl*72 + dl] = lo;
            lhv [dl*72 + nl] = hh;  llv [dl*72 + nl] = lo;
          }
        }
      }
  if (MODE == 1 && Kh){
    __syncthreads();
    const int n = tid>>2, c0q = (tid&3)*16;
    const int bh = (blockIdx.y>>4)*16 + blockIdx.x;
    const int tseq = blockIdx.y & 15;
    const size_t kbase = ((size_t)bh*1024 + tseq*64 + n)*64;
    const int swn = PHI(n)*8;
    const size_t vbase = ((size_t)bh*64 + n)*1024 + tseq*64;
    const int sw2 = (n&7)*8;
    #pragma unroll
    for (int j = 0; j < 2; j++){
      const int db = c0q + j*8;
      *(f16x8*)&Kh[kbase + (db ^ swn)] = *(const f16x8*)&kh_t[n*72 + db];
      *(f16x8*)&Kl[kbase + (db ^ swn)] = *(const f16x8*)&kl_t[n*72 + db];
      *(f16x8*)&Vh[vbase + (db ^ sw2)] = *(const f16x8*)&lhv[n*72 + db];
      *(f16x8*)&Vl[vbase + (db ^ sw2)] = *(const f16x8*)&llv[n*72 + db];
    }
  }
}

extern "C" void kernel_launch(void* const* d_in, const int* in_sizes, int n_in,
                              void* d_out, int out_size, void* d_ws, size_t ws_size,
                              hipStream_t stream){
  const float* x_in = (const float*)d_in[0];
  const float* ln_g = (const float*)d_in[1];
  const float* ln_b = (const float*)d_in[2];
  const float* w1   = (const float*)d_in[3];
  const float* w2   = (const float*)d_in[4];
  const float* fg   = (const float*)d_in[5];
  const float* fb   = (const float*)d_in[6];

  char* ws = (char*)d_ws;
  double*   dsum  = (double*)ws;            // 12
  double*   dabs  = (double*)(ws + 96);     // 12
  _Float16* wb = (_Float16*)(ws + 256);     // 12 * 1M fp16 = 24 MB
  size_t o = 256 + 12ull*1048576ull*2ull;
  float* xA = (float*)(ws + o); o += 2048ull*1024*4;
  float* xB = (float*)(ws + o); o += 2048ull*1024*4;
  _Float16* Kh = (_Float16*)(ws + o); o += 2048ull*1024*2;
  _Float16* Kl = (_Float16*)(ws + o); o += 2048ull*1024*2;
  _Float16* Vh = (_Float16*)(ws + o); o += 2048ull*1024*2;
  _Float16* Vl = (_Float16*)(ws + o); o += 2048ull*1024*2;
  _Float16* Ahb = (_Float16*)(ws + o); o += 2048ull*1024*2;
  _Float16* Alb = (_Float16*)(ws + o); o += 2048ull*1024*2;
  _Float16* Ghb = (_Float16*)(ws + o); o += 2048ull*1024*2;
  _Float16* Glb = (_Float16*)(ws + o); o += 2048ull*1024*2;

  hipMemsetAsync(ws, 0, 256, stream);
  k_wstats  <<<dim3(32,12), 256, 0, stream>>>(w1, w2, dsum, dabs);
  k_binarize<<<6144,        256, 0, stream>>>(w1, w2, dsum, wb);
  k_presplit<<<dim3(16,32), 256, 0, stream>>>(x_in, Kh, Kl, Vh, Vl);

  const float* xc = x_in;
  for (int i = 0; i < 6; i++){
    float* xn = (i & 1) ? xB : xA;
    const bool last = (i == 5);
    k_attn    <<<dim3(32,16), 256, 0, stream>>>(Kh, Kl, Vh, Vl, xc, xn);
    k_ln<1>   <<<512, 256, 0, stream>>>(xn, ln_g + (size_t)i*1024, ln_b + (size_t)i*1024,
                                        nullptr, Ahb, Alb);
    k_gemm<0> <<<dim3(16,32), 256, 0, stream>>>(Ahb, Alb, wb + (size_t)i*1048576,
                                                nullptr, Ghb, Glb, &dabs[i],
                                                nullptr, nullptr, nullptr, nullptr);
    k_gemm<1> <<<dim3(16,32), 256, 0, stream>>>(Ghb, Glb, wb + (size_t)(6+i)*1048576,
                                                xn, nullptr, nullptr, &dabs[6+i],
                                                last ? nullptr : Kh, last ? nullptr : Kl,
                                                last ? nullptr : Vh, last ? nullptr : Vl);
    xc = xn;
  }
  k_ln<0><<<512, 256, 0, stream>>>(xc, fg, fb, (float*)d_out, nullptr, nullptr);
}